// Round 7
// baseline (158.782 us; speedup 1.0000x reference)
//
#include <hip/hip_runtime.h>
#include <hip/hip_bf16.h>

// CausalGraphDiscovery on MI355X. f32 buffers holding bf16-rounded values.
// Round 13: single dispatch, producer->graph->consumer FLAGS (r0's proven
// protocol), zero redundant graph recompute.
//   r6 post-mortem: bid-rotation HURT (+6us; lockstep same-line reads get
//   TCC merge+broadcast; staggering raised distinct-line concurrency,
//   FETCH 5.6->9.9MB). Reverted everywhere.
//   Structure: the redundant graph chain (~25-30us of each mech block) is
//   replaced by r0's distributed scheme INSIDE one dispatch:
//     bid 0      graph block: spin 32 producer flags (acquire, r0-proven),
//                sum partials -> corr -> float4-row MLP -> adj/pm/hp,
//                release flag 32. Writes adj + scores diag.
//     bid 1..128 mech block (v=(bid-1)>>3, chunk=(bid-1)&7):
//                [bid<=32: produce av-partials for slice bid-1 FIRST + L3
//                 weight warm (r0 code)]; then ALL pm-independent phase-B
//                 prep (Wm* regs, W2T/B1/B2/W3 LDS, b2r regs, X prefetch);
//                 then ONE thread polls flag 32 RELAXED (+fence after) ->
//                 pm read -> W1 fold -> 8 MFMA passes.
//     bid 129..248 pair block: 2 pairs, lockstep order, depth-2 prefetch,
//                wave-shfl reduce. Independent of graph.
//   Grid 249 <= 256 CUs => all blocks co-resident => flag waits are safe.
//
// d_out (f32): [0,256) adj | [256,131328) predictions | [131328,131584) scores
// ws (f32): [b*272,+272) av partials (b<32) | 8960 PM(240) | 9200 HP(16)
//           | 9400 dummy | 9600 flags(int): [0..31] producer, [32] release

typedef __attribute__((ext_vector_type(8))) short bf16x8;
typedef __attribute__((ext_vector_type(4))) short bf16x4;
typedef __attribute__((ext_vector_type(4))) float f32x4;

#define DEV __device__ __forceinline__
DEV short f2bf(float f){ __hip_bfloat16 h = __float2bfloat16(f); short s; __builtin_memcpy(&s,&h,2); return s; }

#define WS_P1(b)   ((b)*272)
#define WS_PM      8960
#define WS_HP      9200
#define WS_DUMMY   9400
#define WS_FLAG    9600
#define FLAG_MAGIC 0x1357F00D

struct GraphSm {                // graph block (bid 0) only, ~13.8 KB
    float sum1[256];
    float m[16];
    float corr[256];
    float red2[2048];
    float h1[256];
    float h2[128];
    float adj[256];
    float pm[240];
};
struct ProdSm { float av[16*17]; };   // producer stage (bids 1..32)
struct MechSm {
    short W2T[64*136];          // Wm2^T bf16, padded row 136   17408 B
    short H1[8][16*136];        // per-wave h1 staging          34816 B
    float W1[16*128];           // layer-1 weights (mask folded) 8192 B
    float B1[128];
    float B2[64];
    float W3[64];
};                              // 61440 B
struct PairSm {
    float w0[2][32], w1[2][32], bb[2][32], w2[2][32];
    float red0[8], red1[8];
    float b2s[2];
};
union SmU { GraphSm g; ProdSm pr; MechSm m; PairSm p; };

__global__ void __launch_bounds__(512, 2) k_fused(
    const float* __restrict__ data,
    const float* __restrict__ Ws1, const float* __restrict__ bs1,
    const float* __restrict__ Ws2, const float* __restrict__ bs2,
    const float* __restrict__ Ws3, const float* __restrict__ bs3,
    const float* __restrict__ Wm1, const float* __restrict__ bm1,
    const float* __restrict__ Wm2, const float* __restrict__ bm2,
    const float* __restrict__ Wm3, const float* __restrict__ bm3,
    const float* __restrict__ Wt1, const float* __restrict__ bt1,
    const float* __restrict__ Wt2, const float* __restrict__ bt2,
    float* __restrict__ wsf, float* __restrict__ out)
{
    __shared__ __align__(16) SmU sm;
    __shared__ float pmhp[16];          // outside union: survives phase flip
    int tid = threadIdx.x, bid = blockIdx.x;
    int* flags = (int*)(wsf + WS_FLAG);

    if (bid >= 129) {
        // ============ pair MLP block: 2 pairs, lockstep order ===========
        int pb = bid - 129;             // 0..119
        int p0 = pb*2, p1p = p0 + 1;
        int i0 = p0 / 15, jr0 = p0 % 15;
        int j0 = jr0 + (jr0 >= i0 ? 1 : 0);
        int i1 = p1p / 15, jr1 = p1p % 15;
        int j1 = jr1 + (jr1 >= i1 ? 1 : 0);
        if (tid < 64) {
            int pp = tid >> 5, h = tid & 31;
            int p = pb*2 + pp;
            sm.p.w0[pp][h] = Wt1[p*64 + h];
            sm.p.w1[pp][h] = Wt1[p*64 + 32 + h];
            sm.p.bb[pp][h] = bt1[p*32 + h];
            sm.p.w2[pp][h] = Wt2[p*32 + h];
        }
        if (tid < 2) sm.p.b2s[tid] = bt2[pb*2 + tid];
        __syncthreads();
        float b2s0 = sm.p.b2s[0], b2s1 = sm.p.b2s[1];
        float acc0 = 0.f, acc1 = 0.f;
        // depth-2 software pipeline on x loads (lockstep it order)
        float a0A, b0A, a1A, b1A, a0B, b0B, a1B, b1B;
        {
            int s0 = tid;               // it=0
            a0A = data[s0*16 + i0]; b0A = data[s0*16 + j0];
            a1A = data[s0*16 + i1]; b1A = data[s0*16 + j1];
            int s1 = 512 + tid;         // it=1
            a0B = data[s1*16 + i0]; b0B = data[s1*16 + j0];
            a1B = data[s1*16 + i1]; b1B = data[s1*16 + j1];
        }
        for (int it = 0; it < 16; ++it) {
            float xa0 = a0A, xb0 = b0A, xa1 = a1A, xb1 = b1A;
            a0A = a0B; b0A = b0B; a1A = a1B; b1A = b1B;
            if (it < 14) {
                int s = (it + 2)*512 + tid;
                a0B = data[s*16 + i0]; b0B = data[s*16 + j0];
                a1B = data[s*16 + i1]; b1B = data[s*16 + j1];
            }
            float za0=0.f, zb0=0.f, za1=0.f, zb1=0.f;   // 4 indep chains
            #pragma unroll
            for (int h = 0; h < 32; h += 2) {
                float t00 = fmaf(xa0, sm.p.w0[0][h],   fmaf(xb0, sm.p.w1[0][h],   sm.p.bb[0][h]));
                za0 = fmaf(fmaxf(t00, 0.f), sm.p.w2[0][h],   za0);
                float t01 = fmaf(xa0, sm.p.w0[0][h+1], fmaf(xb0, sm.p.w1[0][h+1], sm.p.bb[0][h+1]));
                zb0 = fmaf(fmaxf(t01, 0.f), sm.p.w2[0][h+1], zb0);
                float t10 = fmaf(xa1, sm.p.w0[1][h],   fmaf(xb1, sm.p.w1[1][h],   sm.p.bb[1][h]));
                za1 = fmaf(fmaxf(t10, 0.f), sm.p.w2[1][h],   za1);
                float t11 = fmaf(xa1, sm.p.w0[1][h+1], fmaf(xb1, sm.p.w1[1][h+1], sm.p.bb[1][h+1]));
                zb1 = fmaf(fmaxf(t11, 0.f), sm.p.w2[1][h+1], zb1);
            }
            float z0 = b2s0 + za0 + zb0;
            float z1 = b2s1 + za1 + zb1;
            acc0 += __builtin_amdgcn_rcpf(1.f + __expf(-z0));
            acc1 += __builtin_amdgcn_rcpf(1.f + __expf(-z1));
        }
        // wave shfl-reduce, then tiny LDS reduce
        #pragma unroll
        for (int off = 32; off > 0; off >>= 1) {
            acc0 += __shfl_xor(acc0, off);
            acc1 += __shfl_xor(acc1, off);
        }
        int lane = tid & 63, wid = tid >> 6;
        if (lane == 0) { sm.p.red0[wid] = acc0; sm.p.red1[wid] = acc1; }
        __syncthreads();
        if (tid == 0) {
            float s0 = 0.f, s1 = 0.f;
            #pragma unroll
            for (int w = 0; w < 8; ++w) { s0 += sm.p.red0[w]; s1 += sm.p.red1[w]; }
            out[256 + 131072 + i0*16 + j0] = s0 * (1.f/8192.f);
            out[256 + 131072 + i1*16 + j1] = s1 * (1.f/8192.f);
        }
        return;
    }

    if (bid == 0) {
        // ==================== graph block ================================
        float bs1r = bs1[tid & 255];     // prefetch biases before the spin
        float bs2r = bs2[tid & 127];
        float bs3r = bs3[tid & 255];
        // spin on 32 producer flags (acquire; one block polling — r0-proven)
        if (tid < 32) {
            while (__hip_atomic_load(&flags[tid], __ATOMIC_ACQUIRE,
                                     __HIP_MEMORY_SCOPE_AGENT) != FLAG_MAGIC)
                __builtin_amdgcn_s_sleep(2);
        }
        __syncthreads();
        __threadfence();
        // sum producer partials
        if (tid < 256) {
            float p1 = 0.f;
            #pragma unroll 8
            for (int b = 0; b < 32; ++b) p1 += wsf[WS_P1(b) + tid];
            sm.g.sum1[tid] = p1;
        }
        if (tid < 16) {
            float ms = 0.f;
            #pragma unroll 8
            for (int b = 0; b < 32; ++b) ms += wsf[WS_P1(b) + 256 + tid];
            sm.g.m[tid] = ms * (1.f/512.f);
        }
        __syncthreads();
        if (tid < 256) {
            int ci = tid >> 4, cj = tid & 15;
            float mci = sm.g.m[ci], mcj = sm.g.m[cj];
            float cij = sm.g.sum1[tid]   - 512.f*mci*mcj;
            float cii = sm.g.sum1[ci*17] - 512.f*mci*mci;
            float cjj = sm.g.sum1[cj*17] - 512.f*mcj*mcj;
            float den = sqrtf(fmaxf(cii, 0.f)) * sqrtf(fmaxf(cjj, 0.f));
            sm.g.corr[tid] = (den > 0.f && ci != cj) ? fabsf(cij/den) : 0.f;
        }
        __syncthreads();
        {   // layer1: float4-row, 8 K-splits of 32 (2 serial load groups)
            int o4 = tid & 63, ks = tid >> 6;
            const float* W1p = Ws1 + ks*32*256 + o4*4;
            const float* cp  = sm.g.corr + ks*32;
            float ax=0.f, ay=0.f, az=0.f, aw=0.f;
            float bx=0.f, by=0.f, bz=0.f, bw=0.f;
            #pragma unroll 8
            for (int i = 0; i < 32; i += 2) {
                float4 w0 = *(const float4*)&W1p[(i  )*256];
                float4 w1 = *(const float4*)&W1p[(i+1)*256];
                float c0 = cp[i], c1 = cp[i+1];
                ax=fmaf(c0,w0.x,ax); ay=fmaf(c0,w0.y,ay); az=fmaf(c0,w0.z,az); aw=fmaf(c0,w0.w,aw);
                bx=fmaf(c1,w1.x,bx); by=fmaf(c1,w1.y,by); bz=fmaf(c1,w1.z,bz); bw=fmaf(c1,w1.w,bw);
            }
            float4 r4; r4.x=ax+bx; r4.y=ay+by; r4.z=az+bz; r4.w=aw+bw;
            *(float4*)&sm.g.red2[ks*256 + o4*4] = r4;
        }
        __syncthreads();
        if (tid < 256) {
            float s = bs1r;
            #pragma unroll
            for (int k2 = 0; k2 < 8; ++k2) s += sm.g.red2[k2*256 + tid];
            sm.g.h1[tid] = fmaxf(s, 0.f);
        }
        __syncthreads();
        {   // layer2: 16 K-splits of 16 (1 load group)
            int o4 = tid & 31, ks = tid >> 5;
            const float* W2p = Ws2 + ks*16*128 + o4*4;
            const float* cp  = sm.g.h1 + ks*16;
            float ax=0.f, ay=0.f, az=0.f, aw=0.f;
            float bx=0.f, by=0.f, bz=0.f, bw=0.f;
            #pragma unroll
            for (int i = 0; i < 16; i += 2) {
                float4 w0 = *(const float4*)&W2p[(i  )*128];
                float4 w1 = *(const float4*)&W2p[(i+1)*128];
                float c0 = cp[i], c1 = cp[i+1];
                ax=fmaf(c0,w0.x,ax); ay=fmaf(c0,w0.y,ay); az=fmaf(c0,w0.z,az); aw=fmaf(c0,w0.w,aw);
                bx=fmaf(c1,w1.x,bx); by=fmaf(c1,w1.y,by); bz=fmaf(c1,w1.z,bz); bw=fmaf(c1,w1.w,bw);
            }
            float4 r4; r4.x=ax+bx; r4.y=ay+by; r4.z=az+bz; r4.w=aw+bw;
            *(float4*)&sm.g.red2[ks*128 + o4*4] = r4;
        }
        __syncthreads();
        if (tid < 128) {
            float s = bs2r;
            #pragma unroll
            for (int k2 = 0; k2 < 16; ++k2) s += sm.g.red2[k2*128 + tid];
            sm.g.h2[tid] = fmaxf(s, 0.f);
        }
        __syncthreads();
        {   // layer3: 8 K-splits of 16 (1 load group)
            int o4 = tid & 63, ks = tid >> 6;
            const float* W3p = Ws3 + ks*16*256 + o4*4;
            const float* cp  = sm.g.h2 + ks*16;
            float ax=0.f, ay=0.f, az=0.f, aw=0.f;
            float bx=0.f, by=0.f, bz=0.f, bw=0.f;
            #pragma unroll
            for (int i = 0; i < 16; i += 2) {
                float4 w0 = *(const float4*)&W3p[(i  )*256];
                float4 w1 = *(const float4*)&W3p[(i+1)*256];
                float c0 = cp[i], c1 = cp[i+1];
                ax=fmaf(c0,w0.x,ax); ay=fmaf(c0,w0.y,ay); az=fmaf(c0,w0.z,az); aw=fmaf(c0,w0.w,aw);
                bx=fmaf(c1,w1.x,bx); by=fmaf(c1,w1.y,by); bz=fmaf(c1,w1.z,bz); bw=fmaf(c1,w1.w,bw);
            }
            float4 r4; r4.x=ax+bx; r4.y=ay+by; r4.z=az+bz; r4.w=aw+bw;
            *(float4*)&sm.g.red2[ks*256 + o4*4] = r4;
        }
        __syncthreads();
        if (tid < 256) {
            float z = bs3r;
            #pragma unroll
            for (int k2 = 0; k2 < 8; ++k2) z += sm.g.red2[k2*256 + tid];
            float a = 1.f / (1.f + expf(-z));      // precise: feeds 0.5 threshold
            int r = tid >> 4, cc = tid & 15;
            float adjv = (r < cc) ? a : 0.f;       // triu(adj,1)
            sm.g.adj[tid] = adjv;
            out[tid] = adjv;
        }
        if (tid >= 256 && tid < 272)
            out[256 + 131072 + (tid-256)*17] = 0.f;    // scores diagonal
        __syncthreads();
        if (tid < 240) {
            int vv = tid / 15, p = tid % 15;
            int jj = p + (p >= vv ? 1 : 0);
            float pmv = (sm.g.adj[jj*16 + vv] > 0.5f) ? 1.f : 0.f;
            wsf[WS_PM + tid] = pmv;
            sm.g.pm[tid] = pmv;
        }
        __syncthreads();
        if (tid < 16) {
            float s = 0.f;
            #pragma unroll
            for (int p = 0; p < 15; ++p) s += sm.g.pm[tid*15 + p];
            wsf[WS_HP + tid] = (s > 0.f) ? 1.f : 0.f;
        }
        __syncthreads();
        if (tid == 0) {
            __threadfence();
            __hip_atomic_store(&flags[32], FLAG_MAGIC,
                               __ATOMIC_RELEASE, __HIP_MEMORY_SCOPE_AGENT);
        }
        return;
    }

    // ==================== mech block (v, chunk) =========================
    int v = (bid - 1) >> 3, chunk = (bid - 1) & 7;
    int gs0 = chunk * 1024;                // 1024 samples per block

    if (bid <= 32) {
        // ---- producer: av partials for samples (bid-1)*16 .. +15 (r0) ----
        int b = bid - 1;
        if (tid < 256) {
            int sl = tid >> 4, vv = tid & 15;
            int s = b*16 + sl;
            float acc = 0.f;
            #pragma unroll
            for (int bt = 0; bt < 16; ++bt) acc += data[bt*8192 + s*16 + vv];
            sm.pr.av[sl*17 + vv] = acc * (1.f/16.f);
        }
        __syncthreads();
        if (tid < 256) {
            int i2 = tid >> 4, j2 = tid & 15;
            float p1 = 0.f;
            #pragma unroll
            for (int r = 0; r < 16; ++r) p1 += sm.pr.av[r*17 + i2] * sm.pr.av[r*17 + j2];
            wsf[WS_P1(b) + tid] = p1;
        }
        if (tid < 16) {
            float ms = 0.f;
            #pragma unroll
            for (int r = 0; r < 16; ++r) ms += sm.pr.av[r*17 + tid];
            wsf[WS_P1(b) + 256 + tid] = ms;
        }
        __syncthreads();
        if (tid == 0) {
            __threadfence();
            __hip_atomic_store(&flags[b], FLAG_MAGIC,
                               __ATOMIC_RELEASE, __HIP_MEMORY_SCOPE_AGENT);
        }
        // ---- L3 weight warm (32 blocks x 16KB = all of Ws1/Ws2/Ws3) ----
        unsigned xr = 0;
        { uint4 u = ((const uint4*)Ws1)[b*512 + tid]; xr ^= u.x^u.y^u.z^u.w; }
        if (tid < 256) { uint4 u = ((const uint4*)Ws2)[b*256 + tid];       xr ^= u.x^u.y^u.z^u.w; }
        else           { uint4 u = ((const uint4*)Ws3)[b*256 + tid - 256]; xr ^= u.x^u.y^u.z^u.w; }
        if (xr == 0x9E3779B9u) wsf[WS_DUMMY] = 0.f;   // defeat DCE
    }

    // ---- pm-independent register prefetch -------------------------------
    float pf_wm1[4];
    #pragma unroll
    for (int r = 0; r < 4; ++r) {
        int e = tid + 512*r;               // e < 2048
        int k = e >> 7, h = e & 127;
        pf_wm1[r] = 0.f;
        if (k != v) {
            int p = k - (k > v ? 1 : 0);
            pf_wm1[r] = Wm1[v*1920 + p*128 + h];
        }
    }
    float4 pf_wm2[4];
    {
        const float* wp = Wm2 + v*8192 + tid*16;
        #pragma unroll
        for (int m4 = 0; m4 < 4; ++m4) pf_wm2[m4] = *(const float4*)&wp[m4*4];
    }
    float b1r  = bm1[v*128 + (tid & 127)];
    float b2rv = bm2[v*64  + (tid & 63)];
    float w3r  = Wm3[v*64  + (tid & 63)];
    float bm3v = bm3[v];

    // ---- pm-independent LDS staging -------------------------------------
    #pragma unroll
    for (int m4 = 0; m4 < 4; ++m4) {
        float4 w4 = pf_wm2[m4];
        int e0 = tid*16 + m4*4;
        int h = e0 >> 6;                   // same for all 4 elems
        int jj0 = e0 & 63;
        sm.m.W2T[(jj0+0)*136 + h] = f2bf(w4.x);
        sm.m.W2T[(jj0+1)*136 + h] = f2bf(w4.y);
        sm.m.W2T[(jj0+2)*136 + h] = f2bf(w4.z);
        sm.m.W2T[(jj0+3)*136 + h] = f2bf(w4.w);
    }
    if (tid < 128) sm.m.B1[tid] = b1r;
    else if (tid < 192) sm.m.B2[tid - 128] = b2rv;
    else if (tid < 256) sm.m.W3[tid - 192] = w3r;
    __syncthreads();

    // ---- per-lane register setup + X prefetch (pm-independent) ----------
    int lane = tid & 63, wid = tid >> 6;   // wid 0..7
    int c = lane & 15, q = lane >> 4;
    bf16x8 b2r[16];
    #pragma unroll
    for (int jt = 0; jt < 4; ++jt)
        #pragma unroll
        for (int ks = 0; ks < 4; ++ks)
            b2r[jt*4 + ks] = *(const bf16x8*)&sm.m.W2T[(jt*16 + c)*136 + ks*32 + q*8];
    float w3c[4], b2c[4];
    #pragma unroll
    for (int jt = 0; jt < 4; ++jt) { w3c[jt] = sm.m.W3[jt*16 + c]; b2c[jt] = sm.m.B2[jt*16 + c]; }
    short* h1buf = sm.m.H1[wid];
    bool act = (q < 2);
    float4 u0c, u1c;
    if (act) {
        const float* xp = &data[(gs0 + wid*8*16 + c)*16 + q*8];
        u0c = *(const float4*)xp;
        u1c = *(const float4*)(xp + 4);
    }

    // ---- wait for graph release (1 relaxed poller; fence once after) ----
    if (tid == 0) {
        while (__hip_atomic_load(&flags[32], __ATOMIC_RELAXED,
                                 __HIP_MEMORY_SCOPE_AGENT) != FLAG_MAGIC)
            __builtin_amdgcn_s_sleep(2);
    }
    __syncthreads();
    __threadfence();
    if (tid < 16) pmhp[tid] = (tid < 15) ? wsf[WS_PM + v*15 + tid]
                                         : wsf[WS_HP + v];
    __syncthreads();

    // ---- W1 fold with pm; hp from LDS -----------------------------------
    #pragma unroll
    for (int r = 0; r < 4; ++r) {
        int e = tid + 512*r;
        int k = e >> 7;
        float val = 0.f;
        if (k != v) {
            int p = k - (k > v ? 1 : 0);
            val = pf_wm1[r] * pmhp[p];
        }
        sm.m.W1[e] = val;
    }
    float hp = pmhp[15];
    __syncthreads();

    bf16x8 a1f[8];
    #pragma unroll
    for (int ht = 0; ht < 8; ++ht) {
        #pragma unroll
        for (int jj = 0; jj < 8; ++jj) {
            int k = q*8 + jj;
            float w = (k < 16) ? sm.m.W1[k*128 + ht*16 + c] : 0.f;
            a1f[ht][jj] = f2bf(w);
        }
    }

    // ---------- phase B: bf16-MFMA mech MLP (1024 samples, 8 passes) -----
    for (int stl = 0; stl < 8; ++stl) {
        int st = wid*8 + stl;                       // 0..63
        float4 u0 = u0c, u1 = u1c;
        if (stl < 7 && act) {                       // prefetch next pass
            const float* xp = &data[(gs0 + (st+1)*16 + c)*16 + q*8];
            u0c = *(const float4*)xp;
            u1c = *(const float4*)(xp + 4);
        }
        bf16x8 xb;
        #pragma unroll
        for (int i2 = 0; i2 < 8; ++i2) xb[i2] = 0;
        if (act) {
            xb[0] = f2bf(u0.x); xb[1] = f2bf(u0.y);
            xb[2] = f2bf(u0.z); xb[3] = f2bf(u0.w);
            xb[4] = f2bf(u1.x); xb[5] = f2bf(u1.y);
            xb[6] = f2bf(u1.z); xb[7] = f2bf(u1.w);
        }
        f32x4 c1[8];
        #pragma unroll
        for (int ht = 0; ht < 8; ++ht) c1[ht] = *(const f32x4*)&sm.m.B1[ht*16 + q*4];
        #pragma unroll
        for (int ht = 0; ht < 8; ++ht)
            c1[ht] = __builtin_amdgcn_mfma_f32_16x16x32_bf16(a1f[ht], xb, c1[ht], 0, 0, 0);
        #pragma unroll
        for (int ht = 0; ht < 8; ++ht) {
            bf16x4 pk;
            #pragma unroll
            for (int r = 0; r < 4; ++r) pk[r] = f2bf(fmaxf(c1[ht][r], 0.f));
            *(bf16x4*)&h1buf[c*136 + ht*16 + q*4] = pk;
        }
        f32x4 c2[4];
        #pragma unroll
        for (int jt = 0; jt < 4; ++jt) {
            float bi = b2c[jt];
            c2[jt] = (f32x4){bi, bi, bi, bi};
        }
        #pragma unroll
        for (int ks = 0; ks < 4; ++ks) {
            bf16x8 a2 = *(const bf16x8*)&h1buf[c*136 + ks*32 + q*8];
            #pragma unroll
            for (int jt = 0; jt < 4; ++jt)
                c2[jt] = __builtin_amdgcn_mfma_f32_16x16x32_bf16(a2, b2r[jt*4 + ks], c2[jt], 0, 0, 0);
        }
        float part[4];
        #pragma unroll
        for (int r = 0; r < 4; ++r) part[r] = 0.f;
        #pragma unroll
        for (int jt = 0; jt < 4; ++jt)
            #pragma unroll
            for (int r = 0; r < 4; ++r)
                part[r] = fmaf(fmaxf(c2[jt][r], 0.f), w3c[jt], part[r]);
        #pragma unroll
        for (int off = 1; off < 16; off <<= 1)
            #pragma unroll
            for (int r = 0; r < 4; ++r)
                part[r] += __shfl_xor(part[r], off, 16);
        if (c == 0) {
            #pragma unroll
            for (int r = 0; r < 4; ++r) {
                int s_loc = st*16 + q*4 + r;
                float mech = part[r] + bm3v;
                float xv = data[(gs0 + s_loc)*16 + v];   // f32 exact fallback
                out[256 + (gs0 + s_loc)*16 + v] = (hp != 0.f) ? mech : xv;
            }
        }
    }
}

// ---------------------------------------------------------------- launch
extern "C" void kernel_launch(void* const* d_in, const int* in_sizes, int n_in,
                              void* d_out, int out_size, void* d_ws, size_t ws_size,
                              hipStream_t stream)
{
    const float* data = (const float*)d_in[0];
    const float* Ws1  = (const float*)d_in[1];
    const float* bs1  = (const float*)d_in[2];
    const float* Ws2  = (const float*)d_in[3];
    const float* bs2  = (const float*)d_in[4];
    const float* Ws3  = (const float*)d_in[5];
    const float* bs3  = (const float*)d_in[6];
    const float* Wm1  = (const float*)d_in[7];
    const float* bm1  = (const float*)d_in[8];
    const float* Wm2  = (const float*)d_in[9];
    const float* bm2  = (const float*)d_in[10];
    const float* Wm3  = (const float*)d_in[11];
    const float* bm3  = (const float*)d_in[12];
    const float* Wt1  = (const float*)d_in[13];
    const float* bt1  = (const float*)d_in[14];
    const float* Wt2  = (const float*)d_in[15];
    const float* bt2  = (const float*)d_in[16];
    float* wsf = (float*)d_ws;
    float* out = (float*)d_out;
    (void)in_sizes; (void)n_in; (void)out_size; (void)ws_size;

    hipLaunchKernelGGL(k_fused, dim3(249), dim3(512), 0, stream,
                       data, Ws1, bs1, Ws2, bs2, Ws3, bs3,
                       Wm1, bm1, Wm2, bm2, Wm3, bm3,
                       Wt1, bt1, Wt2, bt2, wsf, out);
}

// Round 8
// 138.612 us; speedup vs baseline: 1.1455x; 1.1455x over previous
//
#include <hip/hip_runtime.h>
#include <hip/hip_bf16.h>

// CausalGraphDiscovery on MI355X. f32 buffers holding bf16-rounded values.
// Round 14: revert to r5 structure (best: 115.5us, kernel ~40us) + hide the
// Ws2/Ws3 serial rounds in registers.
//   r7 post-mortem: in-dispatch flag protocol DISQUALIFIED (steady 78us,
//   one 40.7ms spin pathology, fence-forced 14MB writebacks).
//   r6 post-mortem: lockstep same-line streams are GOOD (TCC merge);
//   rotation reverted everywhere.
//   Phase split estimate (r2 vs r5): phase B ~4us, phase A ~35us = 4 serial
//   global rounds (data, Ws1, Ws2, Ws3) x ~3-4us contended latency each.
//   Weight ADDRESSES are activation-independent -> issue Ws2+Ws3 float4
//   loads right after A1 (32 float4 = 128 VGPR held ~10us), consume in
//   L2/L3. Two serial rounds removed. launch_bounds(512,1): free, since
//   grid 248 <= 256 CUs => 1 block/CU regardless; VGPR cap 256.
//   Pair blocks: 2 pairs/block (halved data traffic), LOCKSTEP it-order,
//   depth-2 prefetch, wave-shfl reduce.
//
// Grid: 248 blocks x 512 threads.
//   bid   0..127: mech block (v = bid>>3, chunk = bid&7 -> 1024 samples)
//   bid 128..247: pair block, pairs {2*(bid-128), 2*(bid-128)+1}
//   bid 0 additionally writes adj + scores diagonal.
//
// d_out (f32): [0,256) adj | [256,131328) predictions | [131328,131584) scores
// d_ws: UNUSED.

typedef __attribute__((ext_vector_type(8))) short bf16x8;
typedef __attribute__((ext_vector_type(4))) short bf16x4;
typedef __attribute__((ext_vector_type(4))) float f32x4;

#define DEV __device__ __forceinline__
DEV short f2bf(float f){ __hip_bfloat16 h = __float2bfloat16(f); short s; __builtin_memcpy(&s,&h,2); return s; }

// ---- LDS union ----
struct GraphSm {
    float avT[16 * 532];   // av transposed: avT[v][s]; later red2 scratch
    float part[512];       // cov partials
    float corr[256];
    float h1[256];
    float h2[128];         // per-var partials, later layer-2 output
    float adj[256];
};                          // 39680 B
struct MechSm {
    short W2T[64 * 136];    // Wm2^T bf16, padded row 136       17408 B
    short H1[8][16 * 136];  // per-wave h1 staging              34816 B
    float W1[16 * 128];     // layer-1 weights, mask+self folded 8192 B
    float B1[128];
    float B2[64];
    float W3[64];
};                          // 61440 B
struct PairSm {
    float w0[2][32], w1[2][32], bb[2][32], w2[2][32];
    float red0[8], red1[8];
    float b2s[2];
};
union SmU { GraphSm g; MechSm m; PairSm p; };

__global__ void __launch_bounds__(512, 1) k_fused(
    const float* __restrict__ data,
    const float* __restrict__ Ws1, const float* __restrict__ bs1,
    const float* __restrict__ Ws2, const float* __restrict__ bs2,
    const float* __restrict__ Ws3, const float* __restrict__ bs3,
    const float* __restrict__ Wm1, const float* __restrict__ bm1,
    const float* __restrict__ Wm2, const float* __restrict__ bm2,
    const float* __restrict__ Wm3, const float* __restrict__ bm3,
    const float* __restrict__ Wt1, const float* __restrict__ bt1,
    const float* __restrict__ Wt2, const float* __restrict__ bt2,
    float* __restrict__ out)
{
    __shared__ __align__(16) SmU sm;
    int tid = threadIdx.x, bid = blockIdx.x;

    if (bid >= 128) {
        // ============ pair MLP block: 2 pairs, LOCKSTEP order ===========
        int pb = bid - 128;             // 0..119
        int p0 = pb*2, p1p = p0 + 1;
        int i0 = p0 / 15, jr0 = p0 % 15;
        int j0 = jr0 + (jr0 >= i0 ? 1 : 0);
        int i1 = p1p / 15, jr1 = p1p % 15;
        int j1 = jr1 + (jr1 >= i1 ? 1 : 0);
        if (tid < 64) {
            int pp = tid >> 5, h = tid & 31;
            int p = pb*2 + pp;
            sm.p.w0[pp][h] = Wt1[p*64 + h];
            sm.p.w1[pp][h] = Wt1[p*64 + 32 + h];
            sm.p.bb[pp][h] = bt1[p*32 + h];
            sm.p.w2[pp][h] = Wt2[p*32 + h];
        }
        if (tid < 2) sm.p.b2s[tid] = bt2[pb*2 + tid];
        __syncthreads();
        float b2s0 = sm.p.b2s[0], b2s1 = sm.p.b2s[1];
        float acc0 = 0.f, acc1 = 0.f;
        // depth-2 software pipeline on x loads, lockstep it-order
        float a0A, b0A, a1A, b1A, a0B, b0B, a1B, b1B;
        {
            int s0 = tid;
            a0A = data[s0*16 + i0]; b0A = data[s0*16 + j0];
            a1A = data[s0*16 + i1]; b1A = data[s0*16 + j1];
            int s1 = 512 + tid;
            a0B = data[s1*16 + i0]; b0B = data[s1*16 + j0];
            a1B = data[s1*16 + i1]; b1B = data[s1*16 + j1];
        }
        for (int it = 0; it < 16; ++it) {
            float xa0 = a0A, xb0 = b0A, xa1 = a1A, xb1 = b1A;
            a0A = a0B; b0A = b0B; a1A = a1B; b1A = b1B;
            if (it < 14) {
                int s = (it + 2)*512 + tid;
                a0B = data[s*16 + i0]; b0B = data[s*16 + j0];
                a1B = data[s*16 + i1]; b1B = data[s*16 + j1];
            }
            float za0=0.f, zb0=0.f, za1=0.f, zb1=0.f;   // 4 indep chains
            #pragma unroll
            for (int h = 0; h < 32; h += 2) {
                float t00 = fmaf(xa0, sm.p.w0[0][h],   fmaf(xb0, sm.p.w1[0][h],   sm.p.bb[0][h]));
                za0 = fmaf(fmaxf(t00, 0.f), sm.p.w2[0][h],   za0);
                float t01 = fmaf(xa0, sm.p.w0[0][h+1], fmaf(xb0, sm.p.w1[0][h+1], sm.p.bb[0][h+1]));
                zb0 = fmaf(fmaxf(t01, 0.f), sm.p.w2[0][h+1], zb0);
                float t10 = fmaf(xa1, sm.p.w0[1][h],   fmaf(xb1, sm.p.w1[1][h],   sm.p.bb[1][h]));
                za1 = fmaf(fmaxf(t10, 0.f), sm.p.w2[1][h],   za1);
                float t11 = fmaf(xa1, sm.p.w0[1][h+1], fmaf(xb1, sm.p.w1[1][h+1], sm.p.bb[1][h+1]));
                zb1 = fmaf(fmaxf(t11, 0.f), sm.p.w2[1][h+1], zb1);
            }
            float z0 = b2s0 + za0 + zb0;
            float z1 = b2s1 + za1 + zb1;
            acc0 += __builtin_amdgcn_rcpf(1.f + __expf(-z0));
            acc1 += __builtin_amdgcn_rcpf(1.f + __expf(-z1));
        }
        #pragma unroll
        for (int off = 32; off > 0; off >>= 1) {
            acc0 += __shfl_xor(acc0, off);
            acc1 += __shfl_xor(acc1, off);
        }
        int lane = tid & 63, wid = tid >> 6;
        if (lane == 0) { sm.p.red0[wid] = acc0; sm.p.red1[wid] = acc1; }
        __syncthreads();
        if (tid == 0) {
            float s0 = 0.f, s1 = 0.f;
            #pragma unroll
            for (int w = 0; w < 8; ++w) { s0 += sm.p.red0[w]; s1 += sm.p.red1[w]; }
            out[256 + 131072 + i0*16 + j0] = s0 * (1.f/8192.f);
            out[256 + 131072 + i1*16 + j1] = s1 * (1.f/8192.f);
        }
        return;
    }

    // ==================== mech block (v, chunk) =========================
    int v = bid >> 3, chunk = bid & 7;
    int gs0 = chunk * 1024;                // 1024 samples per block

    // ---- t=0 prefetch: phase-B weights + graph biases (no dependencies) --
    float pf_wm1[4];
    #pragma unroll
    for (int r = 0; r < 4; ++r) {
        int e = tid + 512*r;               // e < 2048
        int k = e >> 7, h = e & 127;
        pf_wm1[r] = 0.f;
        if (k != v) {
            int p = k - (k > v ? 1 : 0);
            pf_wm1[r] = Wm1[v*1920 + p*128 + h];
        }
    }
    float4 pf_wm2[4];
    {
        const float* wp = Wm2 + v*8192 + tid*16;
        #pragma unroll
        for (int m4 = 0; m4 < 4; ++m4) pf_wm2[m4] = *(const float4*)&wp[m4*4];
    }
    float b1r  = bm1[v*128 + (tid & 127)];
    float b2r_ = bm2[v*64  + (tid & 63)];
    float w3r  = Wm3[v*64  + (tid & 63)];
    float bm3v = bm3[v];
    float bs1r = bs1[tid & 255];
    float bs2r = bs2[tid & 127];
    float bs3r = bs3[tid & 255];

    // ---------- phase A: redundant graph chain (all f32) -----------------
    {   // S1: av[v][s] = mean over 16 batches; coalesced float4 loads
        int vb = (tid & 3) * 4, sg = tid >> 2;     // sg in 0..127
        for (int k = 0; k < 4; ++k) {
            int s = sg + k*128;
            float ax=0.f, ay=0.f, az=0.f, aw=0.f;
            #pragma unroll
            for (int b = 0; b < 16; ++b) {
                float4 d4 = *(const float4*)&data[b*8192 + s*16 + vb];
                ax += d4.x; ay += d4.y; az += d4.z; aw += d4.w;
            }
            sm.g.avT[(vb+0)*532 + s] = ax * 0.0625f;
            sm.g.avT[(vb+1)*532 + s] = ay * 0.0625f;
            sm.g.avT[(vb+2)*532 + s] = az * 0.0625f;
            sm.g.avT[(vb+3)*532 + s] = aw * 0.0625f;
        }
    }
    __syncthreads();

    // ---- issue Ws2/Ws3 prefetch NOW (addresses activation-independent;
    //      consumed in S7/S9, ~10us later -> latency fully hidden) --------
    float4 pw2[16];
    {
        int o4 = tid & 31, ks = tid >> 5;          // S7 (layer2) mapping
        const float* W2p = Ws2 + ks*16*128 + o4*4;
        #pragma unroll
        for (int i = 0; i < 16; ++i) pw2[i] = *(const float4*)&W2p[i*128];
    }
    float4 pw3[16];
    {
        int o4 = tid & 63, ks = tid >> 6;          // S9 (layer3) mapping
        const float* W3p = Ws3 + ks*16*256 + o4*4;
        #pragma unroll
        for (int i = 0; i < 16; ++i) pw3[i] = *(const float4*)&W3p[i*256];
    }

    // S2: per-variable partial sums over SEQ -> h2[128] (scratch)
    if (tid < 128) {
        int vv = tid >> 3, sgm = tid & 7;
        const float* rp = &sm.g.avT[vv*532 + sgm*64];
        float a0=0.f, a1=0.f, a2=0.f, a3=0.f;
        for (int s = 0; s < 64; s += 4) {
            float4 fa = *(const float4*)&rp[s];
            a0 += fa.x; a1 += fa.y; a2 += fa.z; a3 += fa.w;
        }
        sm.g.h2[tid] = (a0+a1)+(a2+a3);
    }
    __syncthreads();
    // S3: cov partials (s-range split in 2) + per-thread means into regs
    int ci, cj; float mci, mcj;
    {
        int t = tid & 255, hh = tid >> 8;
        ci = t >> 4; cj = t & 15;
        mci = 0.f; mcj = 0.f;
        #pragma unroll
        for (int q = 0; q < 8; ++q) { mci += sm.g.h2[ci*8 + q]; mcj += sm.g.h2[cj*8 + q]; }
        mci *= (1.f/512.f); mcj *= (1.f/512.f);
        const float* pi_ = &sm.g.avT[ci*532 + hh*256];
        const float* pj_ = &sm.g.avT[cj*532 + hh*256];
        float a0=0.f, a1=0.f, a2=0.f, a3=0.f;
        #pragma unroll 4
        for (int s = 0; s < 256; s += 4) {
            float4 fa = *(const float4*)&pi_[s];
            float4 fb = *(const float4*)&pj_[s];
            a0 = fmaf(fa.x, fb.x, a0); a1 = fmaf(fa.y, fb.y, a1);
            a2 = fmaf(fa.z, fb.z, a2); a3 = fmaf(fa.w, fb.w, a3);
        }
        sm.g.part[tid] = (a0+a1)+(a2+a3);
    }
    __syncthreads();
    // S4: corr directly (per-thread redundant diag cov)
    if (tid < 256) {
        float cij = sm.g.part[tid] + sm.g.part[256 + tid] - 512.f*mci*mcj;
        float cii = sm.g.part[ci*17] + sm.g.part[256 + ci*17] - 512.f*mci*mci;
        float cjj = sm.g.part[cj*17] + sm.g.part[256 + cj*17] - 512.f*mcj*mcj;
        float den = sqrtf(fmaxf(cii, 0.f)) * sqrtf(fmaxf(cjj, 0.f));
        sm.g.corr[tid] = (den > 0.f && ci != cj) ? fabsf(cij/den) : 0.f;
    }
    __syncthreads();

    float* red2 = sm.g.avT;     // avT dead after S3: reuse as K-split scratch

    {   // S5 layer1: 256 outs; float4-row loads, 8 K-splits of 32
        int o4 = tid & 63, ks = tid >> 6;
        const float* W1p = Ws1 + ks*32*256 + o4*4;
        const float* cp  = sm.g.corr + ks*32;
        float ax=0.f, ay=0.f, az=0.f, aw=0.f;
        float bx=0.f, by=0.f, bz=0.f, bw=0.f;
        #pragma unroll 4
        for (int i = 0; i < 32; i += 2) {
            float4 w0 = *(const float4*)&W1p[(i  )*256];
            float4 w1 = *(const float4*)&W1p[(i+1)*256];
            float c0 = cp[i], c1 = cp[i+1];
            ax=fmaf(c0,w0.x,ax); ay=fmaf(c0,w0.y,ay); az=fmaf(c0,w0.z,az); aw=fmaf(c0,w0.w,aw);
            bx=fmaf(c1,w1.x,bx); by=fmaf(c1,w1.y,by); bz=fmaf(c1,w1.z,bz); bw=fmaf(c1,w1.w,bw);
        }
        float4 r4; r4.x=ax+bx; r4.y=ay+by; r4.z=az+bz; r4.w=aw+bw;
        *(float4*)&red2[ks*256 + o4*4] = r4;
    }
    __syncthreads();
    // S6: h1 reduce (+prefetched bs1)
    if (tid < 256) {
        float s = bs1r;
        #pragma unroll
        for (int k2 = 0; k2 < 8; ++k2) s += red2[k2*256 + tid];
        sm.g.h1[tid] = fmaxf(s, 0.f);
    }
    __syncthreads();
    {   // S7 layer2: 128 outs; 16 K-splits of 16 — weights from pw2 regs
        int o4 = tid & 31, ks = tid >> 5;
        const float* cp  = sm.g.h1 + ks*16;
        float ax=0.f, ay=0.f, az=0.f, aw=0.f;
        float bx=0.f, by=0.f, bz=0.f, bw=0.f;
        #pragma unroll
        for (int i = 0; i < 16; i += 2) {
            float4 w0 = pw2[i];
            float4 w1 = pw2[i+1];
            float c0 = cp[i], c1 = cp[i+1];
            ax=fmaf(c0,w0.x,ax); ay=fmaf(c0,w0.y,ay); az=fmaf(c0,w0.z,az); aw=fmaf(c0,w0.w,aw);
            bx=fmaf(c1,w1.x,bx); by=fmaf(c1,w1.y,by); bz=fmaf(c1,w1.z,bz); bw=fmaf(c1,w1.w,bw);
        }
        float4 r4; r4.x=ax+bx; r4.y=ay+by; r4.z=az+bz; r4.w=aw+bw;
        *(float4*)&red2[ks*128 + o4*4] = r4;
    }
    __syncthreads();
    // S8: h2 reduce (+prefetched bs2)
    if (tid < 128) {
        float s = bs2r;
        #pragma unroll
        for (int k2 = 0; k2 < 16; ++k2) s += red2[k2*128 + tid];
        sm.g.h2[tid] = fmaxf(s, 0.f);
    }
    __syncthreads();
    {   // S9 layer3: 256 outs; 8 K-splits of 16 — weights from pw3 regs
        int o4 = tid & 63, ks = tid >> 6;
        const float* cp  = sm.g.h2 + ks*16;
        float ax=0.f, ay=0.f, az=0.f, aw=0.f;
        float bx=0.f, by=0.f, bz=0.f, bw=0.f;
        #pragma unroll
        for (int i = 0; i < 16; i += 2) {
            float4 w0 = pw3[i];
            float4 w1 = pw3[i+1];
            float c0 = cp[i], c1 = cp[i+1];
            ax=fmaf(c0,w0.x,ax); ay=fmaf(c0,w0.y,ay); az=fmaf(c0,w0.z,az); aw=fmaf(c0,w0.w,aw);
            bx=fmaf(c1,w1.x,bx); by=fmaf(c1,w1.y,by); bz=fmaf(c1,w1.z,bz); bw=fmaf(c1,w1.w,bw);
        }
        float4 r4; r4.x=ax+bx; r4.y=ay+by; r4.z=az+bz; r4.w=aw+bw;
        *(float4*)&red2[ks*256 + o4*4] = r4;
    }
    __syncthreads();
    // S10: adj (+prefetched bs3)
    if (tid < 256) {
        float z = bs3r;
        #pragma unroll
        for (int k2 = 0; k2 < 8; ++k2) z += red2[k2*256 + tid];
        float a = 1.f / (1.f + expf(-z));          // precise: feeds 0.5 threshold
        int r = tid >> 4, cc = tid & 15;
        float adjv = (r < cc) ? a : 0.f;           // triu(adj,1)
        sm.g.adj[tid] = adjv;
        if (bid == 0) out[tid] = adjv;             // one block owns adj write
    }
    if (bid == 0 && tid >= 256 && tid < 272)
        out[256 + 131072 + (tid-256)*17] = 0.f;    // scores diagonal
    __syncthreads();

    // S11: phase-B LDS staging purely from prefetched registers + adj reads.
    #pragma unroll
    for (int r = 0; r < 4; ++r) {
        int e = tid + 512*r;
        int k = e >> 7;
        float val = 0.f;
        if (k != v && sm.g.adj[k*16 + v] > 0.5f) val = pf_wm1[r];
        sm.m.W1[e] = val;
    }
    float hp = 0.f;
    #pragma unroll
    for (int k = 0; k < 16; ++k)
        if (k != v && sm.g.adj[k*16 + v] > 0.5f) hp = 1.f;
    #pragma unroll
    for (int m4 = 0; m4 < 4; ++m4) {
        float4 w4 = pf_wm2[m4];
        int e0 = tid*16 + m4*4;
        int h = e0 >> 6;
        int jj0 = e0 & 63;
        sm.m.W2T[(jj0+0)*136 + h] = f2bf(w4.x);
        sm.m.W2T[(jj0+1)*136 + h] = f2bf(w4.y);
        sm.m.W2T[(jj0+2)*136 + h] = f2bf(w4.z);
        sm.m.W2T[(jj0+3)*136 + h] = f2bf(w4.w);
    }
    if (tid < 128) sm.m.B1[tid] = b1r;
    else if (tid < 192) sm.m.B2[tid - 128] = b2r_;
    else if (tid < 256) sm.m.W3[tid - 192] = w3r;
    __syncthreads();

    // ---------- phase B: bf16-MFMA mech MLP (1024 samples) ---------------
    int lane = tid & 63, wid = tid >> 6;           // wid 0..7
    int c = lane & 15, q = lane >> 4;

    bf16x8 a1f[8];
    #pragma unroll
    for (int ht = 0; ht < 8; ++ht) {
        #pragma unroll
        for (int jj = 0; jj < 8; ++jj) {
            int k = q*8 + jj;
            float w = (k < 16) ? sm.m.W1[k*128 + ht*16 + c] : 0.f;
            a1f[ht][jj] = f2bf(w);
        }
    }
    bf16x8 b2r[16];
    #pragma unroll
    for (int jt = 0; jt < 4; ++jt)
        #pragma unroll
        for (int ks = 0; ks < 4; ++ks)
            b2r[jt*4 + ks] = *(const bf16x8*)&sm.m.W2T[(jt*16 + c)*136 + ks*32 + q*8];
    float w3c[4], b2c[4];
    #pragma unroll
    for (int jt = 0; jt < 4; ++jt) { w3c[jt] = sm.m.W3[jt*16 + c]; b2c[jt] = sm.m.B2[jt*16 + c]; }

    short* h1buf = sm.m.H1[wid];
    bool act = (q < 2);

    // 1-ahead software pipeline on the X-tile loads
    float4 u0c, u1c;
    {
        int st0 = wid*8;
        if (act) {
            const float* xp = &data[(gs0 + st0*16 + c)*16 + q*8];
            u0c = *(const float4*)xp;
            u1c = *(const float4*)(xp + 4);
        }
    }

    for (int stl = 0; stl < 8; ++stl) {
        int st = wid*8 + stl;                       // 0..63 (1024 samples)
        float4 u0 = u0c, u1 = u1c;
        if (stl < 7 && act) {                       // prefetch next pass
            const float* xp = &data[(gs0 + (st+1)*16 + c)*16 + q*8];
            u0c = *(const float4*)xp;
            u1c = *(const float4*)(xp + 4);
        }
        bf16x8 xb;
        #pragma unroll
        for (int i2 = 0; i2 < 8; ++i2) xb[i2] = 0;
        if (act) {
            xb[0] = f2bf(u0.x); xb[1] = f2bf(u0.y);
            xb[2] = f2bf(u0.z); xb[3] = f2bf(u0.w);
            xb[4] = f2bf(u1.x); xb[5] = f2bf(u1.y);
            xb[6] = f2bf(u1.z); xb[7] = f2bf(u1.w);
        }
        f32x4 c1[8];
        #pragma unroll
        for (int ht = 0; ht < 8; ++ht) c1[ht] = *(const f32x4*)&sm.m.B1[ht*16 + q*4];
        #pragma unroll
        for (int ht = 0; ht < 8; ++ht)
            c1[ht] = __builtin_amdgcn_mfma_f32_16x16x32_bf16(a1f[ht], xb, c1[ht], 0, 0, 0);
        #pragma unroll
        for (int ht = 0; ht < 8; ++ht) {
            bf16x4 pk;
            #pragma unroll
            for (int r = 0; r < 4; ++r) pk[r] = f2bf(fmaxf(c1[ht][r], 0.f));
            *(bf16x4*)&h1buf[c*136 + ht*16 + q*4] = pk;
        }
        f32x4 c2[4];
        #pragma unroll
        for (int jt = 0; jt < 4; ++jt) {
            float bi = b2c[jt];
            c2[jt] = (f32x4){bi, bi, bi, bi};
        }
        #pragma unroll
        for (int ks = 0; ks < 4; ++ks) {
            bf16x8 a2 = *(const bf16x8*)&h1buf[c*136 + ks*32 + q*8];
            #pragma unroll
            for (int jt = 0; jt < 4; ++jt)
                c2[jt] = __builtin_amdgcn_mfma_f32_16x16x32_bf16(a2, b2r[jt*4 + ks], c2[jt], 0, 0, 0);
        }
        float part[4];
        #pragma unroll
        for (int r = 0; r < 4; ++r) part[r] = 0.f;
        #pragma unroll
        for (int jt = 0; jt < 4; ++jt)
            #pragma unroll
            for (int r = 0; r < 4; ++r)
                part[r] = fmaf(fmaxf(c2[jt][r], 0.f), w3c[jt], part[r]);
        #pragma unroll
        for (int off = 1; off < 16; off <<= 1)
            #pragma unroll
            for (int r = 0; r < 4; ++r)
                part[r] += __shfl_xor(part[r], off, 16);
        if (c == 0) {
            #pragma unroll
            for (int r = 0; r < 4; ++r) {
                int s_loc = st*16 + q*4 + r;
                float mech = part[r] + bm3v;
                float xv = data[(gs0 + s_loc)*16 + v];   // f32 exact fallback
                out[256 + (gs0 + s_loc)*16 + v] = (hp != 0.f) ? mech : xv;
            }
        }
    }
}

// ---------------------------------------------------------------- launch
extern "C" void kernel_launch(void* const* d_in, const int* in_sizes, int n_in,
                              void* d_out, int out_size, void* d_ws, size_t ws_size,
                              hipStream_t stream)
{
    const float* data = (const float*)d_in[0];
    const float* Ws1  = (const float*)d_in[1];
    const float* bs1  = (const float*)d_in[2];
    const float* Ws2  = (const float*)d_in[3];
    const float* bs2  = (const float*)d_in[4];
    const float* Ws3  = (const float*)d_in[5];
    const float* bs3  = (const float*)d_in[6];
    const float* Wm1  = (const float*)d_in[7];
    const float* bm1  = (const float*)d_in[8];
    const float* Wm2  = (const float*)d_in[9];
    const float* bm2  = (const float*)d_in[10];
    const float* Wm3  = (const float*)d_in[11];
    const float* bm3  = (const float*)d_in[12];
    const float* Wt1  = (const float*)d_in[13];
    const float* bt1  = (const float*)d_in[14];
    const float* Wt2  = (const float*)d_in[15];
    const float* bt2  = (const float*)d_in[16];
    float* out = (float*)d_out;
    (void)d_ws; (void)ws_size; (void)in_sizes; (void)n_in; (void)out_size;

    hipLaunchKernelGGL(k_fused, dim3(248), dim3(512), 0, stream,
                       data, Ws1, bs1, Ws2, bs2, Ws3, bs3,
                       Wm1, bm1, Wm2, bm2, Wm3, bm3,
                       Wt1, bt1, Wt2, bt2, out);
}

// Round 9
// 135.785 us; speedup vs baseline: 1.1694x; 1.0208x over previous
//
#include <hip/hip_runtime.h>
#include <hip/hip_bf16.h>

// CausalGraphDiscovery on MI355X. f32 buffers holding bf16-rounded values.
// Round 15: exact r5 (=round-11) mech path + merged lockstep pair blocks.
//   r8 post-mortem: compiler caps VGPR at 128 regardless of launch_bounds
//   (512,1); pw2[16]+pw3[16] prefetch spilled (WRITE 1->12MB, 40->59us).
//   Register residency across stages is DISQUALIFIED (3rd failed route,
//   after r6 stream-rotation and r7 in-dispatch flags).
//   This round, single variable vs r5: pair blocks merged 2-per-block
//   (240->120 full-dataset request streams concurrent with mech A1;
//   lockstep it-order preserved -- r6 showed lockstep gets TCC merge),
//   grid 368->248 <= 256 CUs. Mech path is BIT-IDENTICAL to r5
//   (launch_bounds(512,2), VGPR 88, no spill).
//
// Grid: 248 blocks x 512 threads.
//   bid   0..127: mech block (v = bid>>3, chunk = bid&7 -> 1024 samples)
//   bid 128..247: pair block, pairs {2*(bid-128), 2*(bid-128)+1}
//   bid 0 additionally writes adj + scores diagonal.
//
// d_out (f32): [0,256) adj | [256,131328) predictions | [131328,131584) scores
// d_ws: UNUSED.

typedef __attribute__((ext_vector_type(8))) short bf16x8;
typedef __attribute__((ext_vector_type(4))) short bf16x4;
typedef __attribute__((ext_vector_type(4))) float f32x4;

#define DEV __device__ __forceinline__
DEV short f2bf(float f){ __hip_bfloat16 h = __float2bfloat16(f); short s; __builtin_memcpy(&s,&h,2); return s; }

// ---- LDS union ----
// avT stride 532: multiple of 4 (16B float4 rows); 532 % 32 == 20 -> cov
// reads ~2-way conflicts (free). avT reused as red2[] K-split scratch.
struct GraphSm {
    float avT[16 * 532];   // av transposed: avT[v][s]; later red2 scratch
    float part[512];       // cov partials
    float corr[256];
    float h1[256];
    float h2[128];         // per-var partials, later layer-2 output
    float adj[256];
};                          // 39680 B
struct MechSm {
    short W2T[64 * 136];    // Wm2^T bf16, padded row 136       17408 B
    short H1[8][16 * 136];  // per-wave h1 staging              34816 B
    float W1[16 * 128];     // layer-1 weights, mask+self folded 8192 B
    float B1[128];
    float B2[64];
    float W3[64];
};                          // 61440 B
struct PairSm {
    float w0[2][32], w1[2][32], bb[2][32], w2[2][32];
    float red0[8], red1[8];
    float b2s[2];
};
union SmU { GraphSm g; MechSm m; PairSm p; };

__global__ void __launch_bounds__(512, 2) k_fused(
    const float* __restrict__ data,
    const float* __restrict__ Ws1, const float* __restrict__ bs1,
    const float* __restrict__ Ws2, const float* __restrict__ bs2,
    const float* __restrict__ Ws3, const float* __restrict__ bs3,
    const float* __restrict__ Wm1, const float* __restrict__ bm1,
    const float* __restrict__ Wm2, const float* __restrict__ bm2,
    const float* __restrict__ Wm3, const float* __restrict__ bm3,
    const float* __restrict__ Wt1, const float* __restrict__ bt1,
    const float* __restrict__ Wt2, const float* __restrict__ bt2,
    float* __restrict__ out)
{
    __shared__ __align__(16) SmU sm;
    int tid = threadIdx.x, bid = blockIdx.x;

    if (bid >= 128) {
        // ============ pair MLP block: 2 pairs, LOCKSTEP order ===========
        int pb = bid - 128;             // 0..119
        int p0 = pb*2, p1p = p0 + 1;
        int i0 = p0 / 15, jr0 = p0 % 15;
        int j0 = jr0 + (jr0 >= i0 ? 1 : 0);
        int i1 = p1p / 15, jr1 = p1p % 15;
        int j1 = jr1 + (jr1 >= i1 ? 1 : 0);
        if (tid < 64) {
            int pp = tid >> 5, h = tid & 31;
            int p = pb*2 + pp;
            sm.p.w0[pp][h] = Wt1[p*64 + h];
            sm.p.w1[pp][h] = Wt1[p*64 + 32 + h];
            sm.p.bb[pp][h] = bt1[p*32 + h];
            sm.p.w2[pp][h] = Wt2[p*32 + h];
        }
        if (tid < 2) sm.p.b2s[tid] = bt2[pb*2 + tid];
        __syncthreads();
        float b2s0 = sm.p.b2s[0], b2s1 = sm.p.b2s[1];
        float acc0 = 0.f, acc1 = 0.f;
        // depth-2 software pipeline on x loads, lockstep it-order
        float a0A, b0A, a1A, b1A, a0B, b0B, a1B, b1B;
        {
            int s0 = tid;
            a0A = data[s0*16 + i0]; b0A = data[s0*16 + j0];
            a1A = data[s0*16 + i1]; b1A = data[s0*16 + j1];
            int s1 = 512 + tid;
            a0B = data[s1*16 + i0]; b0B = data[s1*16 + j0];
            a1B = data[s1*16 + i1]; b1B = data[s1*16 + j1];
        }
        for (int it = 0; it < 16; ++it) {
            float xa0 = a0A, xb0 = b0A, xa1 = a1A, xb1 = b1A;
            a0A = a0B; b0A = b0B; a1A = a1B; b1A = b1B;
            if (it < 14) {
                int s = (it + 2)*512 + tid;
                a0B = data[s*16 + i0]; b0B = data[s*16 + j0];
                a1B = data[s*16 + i1]; b1B = data[s*16 + j1];
            }
            float za0=0.f, zb0=0.f, za1=0.f, zb1=0.f;   // 4 indep chains
            #pragma unroll
            for (int h = 0; h < 32; h += 2) {
                float t00 = fmaf(xa0, sm.p.w0[0][h],   fmaf(xb0, sm.p.w1[0][h],   sm.p.bb[0][h]));
                za0 = fmaf(fmaxf(t00, 0.f), sm.p.w2[0][h],   za0);
                float t01 = fmaf(xa0, sm.p.w0[0][h+1], fmaf(xb0, sm.p.w1[0][h+1], sm.p.bb[0][h+1]));
                zb0 = fmaf(fmaxf(t01, 0.f), sm.p.w2[0][h+1], zb0);
                float t10 = fmaf(xa1, sm.p.w0[1][h],   fmaf(xb1, sm.p.w1[1][h],   sm.p.bb[1][h]));
                za1 = fmaf(fmaxf(t10, 0.f), sm.p.w2[1][h],   za1);
                float t11 = fmaf(xa1, sm.p.w0[1][h+1], fmaf(xb1, sm.p.w1[1][h+1], sm.p.bb[1][h+1]));
                zb1 = fmaf(fmaxf(t11, 0.f), sm.p.w2[1][h+1], zb1);
            }
            float z0 = b2s0 + za0 + zb0;
            float z1 = b2s1 + za1 + zb1;
            acc0 += __builtin_amdgcn_rcpf(1.f + __expf(-z0));
            acc1 += __builtin_amdgcn_rcpf(1.f + __expf(-z1));
        }
        #pragma unroll
        for (int off = 32; off > 0; off >>= 1) {
            acc0 += __shfl_xor(acc0, off);
            acc1 += __shfl_xor(acc1, off);
        }
        int lane = tid & 63, wid = tid >> 6;
        if (lane == 0) { sm.p.red0[wid] = acc0; sm.p.red1[wid] = acc1; }
        __syncthreads();
        if (tid == 0) {
            float s0 = 0.f, s1 = 0.f;
            #pragma unroll
            for (int w = 0; w < 8; ++w) { s0 += sm.p.red0[w]; s1 += sm.p.red1[w]; }
            out[256 + 131072 + i0*16 + j0] = s0 * (1.f/8192.f);
            out[256 + 131072 + i1*16 + j1] = s1 * (1.f/8192.f);
        }
        return;
    }

    // ==================== mech block (v, chunk) — EXACT r5 path =========
    int v = bid >> 3, chunk = bid & 7;
    int gs0 = chunk * 1024;                // 1024 samples per block

    // ---- t=0 prefetch: phase-B weights + graph biases (no dependencies) --
    float pf_wm1[4];
    #pragma unroll
    for (int r = 0; r < 4; ++r) {
        int e = tid + 512*r;               // e < 2048
        int k = e >> 7, h = e & 127;
        pf_wm1[r] = 0.f;
        if (k != v) {
            int p = k - (k > v ? 1 : 0);
            pf_wm1[r] = Wm1[v*1920 + p*128 + h];
        }
    }
    float4 pf_wm2[4];
    {
        const float* wp = Wm2 + v*8192 + tid*16;
        #pragma unroll
        for (int m4 = 0; m4 < 4; ++m4) pf_wm2[m4] = *(const float4*)&wp[m4*4];
    }
    float b1r  = bm1[v*128 + (tid & 127)];
    float b2r_ = bm2[v*64  + (tid & 63)];
    float w3r  = Wm3[v*64  + (tid & 63)];
    float bm3v = bm3[v];
    float bs1r = bs1[tid & 255];
    float bs2r = bs2[tid & 127];
    float bs3r = bs3[tid & 255];

    // ---------- phase A: redundant graph chain (all f32) -----------------
    {   // S1: av[v][s] = mean over 16 batches; coalesced float4 loads
        int vb = (tid & 3) * 4, sg = tid >> 2;     // sg in 0..127
        for (int k = 0; k < 4; ++k) {
            int s = sg + k*128;
            float ax=0.f, ay=0.f, az=0.f, aw=0.f;
            #pragma unroll
            for (int b = 0; b < 16; ++b) {
                float4 d4 = *(const float4*)&data[b*8192 + s*16 + vb];
                ax += d4.x; ay += d4.y; az += d4.z; aw += d4.w;
            }
            sm.g.avT[(vb+0)*532 + s] = ax * 0.0625f;
            sm.g.avT[(vb+1)*532 + s] = ay * 0.0625f;
            sm.g.avT[(vb+2)*532 + s] = az * 0.0625f;
            sm.g.avT[(vb+3)*532 + s] = aw * 0.0625f;
        }
    }
    __syncthreads();
    // S2: per-variable partial sums over SEQ -> h2[128] (scratch)
    if (tid < 128) {
        int vv = tid >> 3, sgm = tid & 7;
        const float* rp = &sm.g.avT[vv*532 + sgm*64];
        float a0=0.f, a1=0.f, a2=0.f, a3=0.f;
        for (int s = 0; s < 64; s += 4) {
            float4 fa = *(const float4*)&rp[s];
            a0 += fa.x; a1 += fa.y; a2 += fa.z; a3 += fa.w;
        }
        sm.g.h2[tid] = (a0+a1)+(a2+a3);
    }
    __syncthreads();
    // S3: cov partials (s-range split in 2) + per-thread means into regs
    int ci, cj; float mci, mcj;
    {
        int t = tid & 255, hh = tid >> 8;
        ci = t >> 4; cj = t & 15;
        mci = 0.f; mcj = 0.f;
        #pragma unroll
        for (int q = 0; q < 8; ++q) { mci += sm.g.h2[ci*8 + q]; mcj += sm.g.h2[cj*8 + q]; }
        mci *= (1.f/512.f); mcj *= (1.f/512.f);
        const float* pi_ = &sm.g.avT[ci*532 + hh*256];
        const float* pj_ = &sm.g.avT[cj*532 + hh*256];
        float a0=0.f, a1=0.f, a2=0.f, a3=0.f;
        #pragma unroll 8
        for (int s = 0; s < 256; s += 4) {
            float4 fa = *(const float4*)&pi_[s];
            float4 fb = *(const float4*)&pj_[s];
            a0 = fmaf(fa.x, fb.x, a0); a1 = fmaf(fa.y, fb.y, a1);
            a2 = fmaf(fa.z, fb.z, a2); a3 = fmaf(fa.w, fb.w, a3);
        }
        sm.g.part[tid] = (a0+a1)+(a2+a3);
    }
    __syncthreads();
    // S4: corr directly (per-thread redundant diag cov)
    if (tid < 256) {
        float cij = sm.g.part[tid] + sm.g.part[256 + tid] - 512.f*mci*mcj;
        float cii = sm.g.part[ci*17] + sm.g.part[256 + ci*17] - 512.f*mci*mci;
        float cjj = sm.g.part[cj*17] + sm.g.part[256 + cj*17] - 512.f*mcj*mcj;
        float den = sqrtf(fmaxf(cii, 0.f)) * sqrtf(fmaxf(cjj, 0.f));
        sm.g.corr[tid] = (den > 0.f && ci != cj) ? fabsf(cij/den) : 0.f;
    }
    __syncthreads();

    float* red2 = sm.g.avT;     // avT dead after S3: reuse as K-split scratch

    {   // S5 layer1: 256 outs; float4-row loads, 8 K-splits of 32
        int o4 = tid & 63, ks = tid >> 6;
        const float* W1p = Ws1 + ks*32*256 + o4*4;
        const float* cp  = sm.g.corr + ks*32;
        float ax=0.f, ay=0.f, az=0.f, aw=0.f;
        float bx=0.f, by=0.f, bz=0.f, bw=0.f;
        #pragma unroll 8
        for (int i = 0; i < 32; i += 2) {
            float4 w0 = *(const float4*)&W1p[(i  )*256];
            float4 w1 = *(const float4*)&W1p[(i+1)*256];
            float c0 = cp[i], c1 = cp[i+1];
            ax=fmaf(c0,w0.x,ax); ay=fmaf(c0,w0.y,ay); az=fmaf(c0,w0.z,az); aw=fmaf(c0,w0.w,aw);
            bx=fmaf(c1,w1.x,bx); by=fmaf(c1,w1.y,by); bz=fmaf(c1,w1.z,bz); bw=fmaf(c1,w1.w,bw);
        }
        float4 r4; r4.x=ax+bx; r4.y=ay+by; r4.z=az+bz; r4.w=aw+bw;
        *(float4*)&red2[ks*256 + o4*4] = r4;
    }
    __syncthreads();
    // S6: h1 reduce (+prefetched bs1)
    if (tid < 256) {
        float s = bs1r;
        #pragma unroll
        for (int k2 = 0; k2 < 8; ++k2) s += red2[k2*256 + tid];
        sm.g.h1[tid] = fmaxf(s, 0.f);
    }
    __syncthreads();
    {   // S7 layer2: 128 outs; 16 K-splits of 16 -> 16 loads/thread, 1 group
        int o4 = tid & 31, ks = tid >> 5;
        const float* W2p = Ws2 + ks*16*128 + o4*4;
        const float* cp  = sm.g.h1 + ks*16;
        float ax=0.f, ay=0.f, az=0.f, aw=0.f;
        float bx=0.f, by=0.f, bz=0.f, bw=0.f;
        #pragma unroll
        for (int i = 0; i < 16; i += 2) {
            float4 w0 = *(const float4*)&W2p[(i  )*128];
            float4 w1 = *(const float4*)&W2p[(i+1)*128];
            float c0 = cp[i], c1 = cp[i+1];
            ax=fmaf(c0,w0.x,ax); ay=fmaf(c0,w0.y,ay); az=fmaf(c0,w0.z,az); aw=fmaf(c0,w0.w,aw);
            bx=fmaf(c1,w1.x,bx); by=fmaf(c1,w1.y,by); bz=fmaf(c1,w1.z,bz); bw=fmaf(c1,w1.w,bw);
        }
        float4 r4; r4.x=ax+bx; r4.y=ay+by; r4.z=az+bz; r4.w=aw+bw;
        *(float4*)&red2[ks*128 + o4*4] = r4;
    }
    __syncthreads();
    // S8: h2 reduce (+prefetched bs2)
    if (tid < 128) {
        float s = bs2r;
        #pragma unroll
        for (int k2 = 0; k2 < 16; ++k2) s += red2[k2*128 + tid];
        sm.g.h2[tid] = fmaxf(s, 0.f);
    }
    __syncthreads();
    {   // S9 layer3: 256 outs; 8 K-splits of 16 -> 16 loads/thread, 1 group
        int o4 = tid & 63, ks = tid >> 6;
        const float* W3p = Ws3 + ks*16*256 + o4*4;
        const float* cp  = sm.g.h2 + ks*16;
        float ax=0.f, ay=0.f, az=0.f, aw=0.f;
        float bx=0.f, by=0.f, bz=0.f, bw=0.f;
        #pragma unroll
        for (int i = 0; i < 16; i += 2) {
            float4 w0 = *(const float4*)&W3p[(i  )*256];
            float4 w1 = *(const float4*)&W3p[(i+1)*256];
            float c0 = cp[i], c1 = cp[i+1];
            ax=fmaf(c0,w0.x,ax); ay=fmaf(c0,w0.y,ay); az=fmaf(c0,w0.z,az); aw=fmaf(c0,w0.w,aw);
            bx=fmaf(c1,w1.x,bx); by=fmaf(c1,w1.y,by); bz=fmaf(c1,w1.z,bz); bw=fmaf(c1,w1.w,bw);
        }
        float4 r4; r4.x=ax+bx; r4.y=ay+by; r4.z=az+bz; r4.w=aw+bw;
        *(float4*)&red2[ks*256 + o4*4] = r4;
    }
    __syncthreads();
    // S10: adj (+prefetched bs3)
    if (tid < 256) {
        float z = bs3r;
        #pragma unroll
        for (int k2 = 0; k2 < 8; ++k2) z += red2[k2*256 + tid];
        float a = 1.f / (1.f + expf(-z));          // precise: feeds 0.5 threshold
        int r = tid >> 4, cc = tid & 15;
        float adjv = (r < cc) ? a : 0.f;           // triu(adj,1)
        sm.g.adj[tid] = adjv;
        if (bid == 0) out[tid] = adjv;             // one block owns adj write
    }
    if (bid == 0 && tid >= 256 && tid < 272)
        out[256 + 131072 + (tid-256)*17] = 0.f;    // scores diagonal
    __syncthreads();

    // S11: phase-B LDS staging purely from prefetched registers + adj reads.
    #pragma unroll
    for (int r = 0; r < 4; ++r) {
        int e = tid + 512*r;
        int k = e >> 7;
        float val = 0.f;
        if (k != v && sm.g.adj[k*16 + v] > 0.5f) val = pf_wm1[r];
        sm.m.W1[e] = val;
    }
    float hp = 0.f;
    #pragma unroll
    for (int k = 0; k < 16; ++k)
        if (k != v && sm.g.adj[k*16 + v] > 0.5f) hp = 1.f;
    #pragma unroll
    for (int m4 = 0; m4 < 4; ++m4) {
        float4 w4 = pf_wm2[m4];
        int e0 = tid*16 + m4*4;
        int h = e0 >> 6;
        int jj0 = e0 & 63;
        sm.m.W2T[(jj0+0)*136 + h] = f2bf(w4.x);
        sm.m.W2T[(jj0+1)*136 + h] = f2bf(w4.y);
        sm.m.W2T[(jj0+2)*136 + h] = f2bf(w4.z);
        sm.m.W2T[(jj0+3)*136 + h] = f2bf(w4.w);
    }
    if (tid < 128) sm.m.B1[tid] = b1r;
    else if (tid < 192) sm.m.B2[tid - 128] = b2r_;
    else if (tid < 256) sm.m.W3[tid - 192] = w3r;
    __syncthreads();

    // ---------- phase B: bf16-MFMA mech MLP (1024 samples) ---------------
    int lane = tid & 63, wid = tid >> 6;           // wid 0..7
    int c = lane & 15, q = lane >> 4;

    bf16x8 a1f[8];
    #pragma unroll
    for (int ht = 0; ht < 8; ++ht) {
        #pragma unroll
        for (int jj = 0; jj < 8; ++jj) {
            int k = q*8 + jj;
            float w = (k < 16) ? sm.m.W1[k*128 + ht*16 + c] : 0.f;
            a1f[ht][jj] = f2bf(w);
        }
    }
    bf16x8 b2r[16];
    #pragma unroll
    for (int jt = 0; jt < 4; ++jt)
        #pragma unroll
        for (int ks = 0; ks < 4; ++ks)
            b2r[jt*4 + ks] = *(const bf16x8*)&sm.m.W2T[(jt*16 + c)*136 + ks*32 + q*8];
    float w3c[4], b2c[4];
    #pragma unroll
    for (int jt = 0; jt < 4; ++jt) { w3c[jt] = sm.m.W3[jt*16 + c]; b2c[jt] = sm.m.B2[jt*16 + c]; }

    short* h1buf = sm.m.H1[wid];
    bool act = (q < 2);

    // 1-ahead software pipeline on the X-tile loads
    float4 u0c, u1c;
    {
        int st0 = wid*8;
        if (act) {
            const float* xp = &data[(gs0 + st0*16 + c)*16 + q*8];
            u0c = *(const float4*)xp;
            u1c = *(const float4*)(xp + 4);
        }
    }

    for (int stl = 0; stl < 8; ++stl) {
        int st = wid*8 + stl;                       // 0..63 (1024 samples)
        float4 u0 = u0c, u1 = u1c;
        if (stl < 7 && act) {                       // prefetch next pass
            const float* xp = &data[(gs0 + (st+1)*16 + c)*16 + q*8];
            u0c = *(const float4*)xp;
            u1c = *(const float4*)(xp + 4);
        }
        bf16x8 xb;
        #pragma unroll
        for (int i2 = 0; i2 < 8; ++i2) xb[i2] = 0;
        if (act) {
            xb[0] = f2bf(u0.x); xb[1] = f2bf(u0.y);
            xb[2] = f2bf(u0.z); xb[3] = f2bf(u0.w);
            xb[4] = f2bf(u1.x); xb[5] = f2bf(u1.y);
            xb[6] = f2bf(u1.z); xb[7] = f2bf(u1.w);
        }
        f32x4 c1[8];
        #pragma unroll
        for (int ht = 0; ht < 8; ++ht) c1[ht] = *(const f32x4*)&sm.m.B1[ht*16 + q*4];
        #pragma unroll
        for (int ht = 0; ht < 8; ++ht)
            c1[ht] = __builtin_amdgcn_mfma_f32_16x16x32_bf16(a1f[ht], xb, c1[ht], 0, 0, 0);
        #pragma unroll
        for (int ht = 0; ht < 8; ++ht) {
            bf16x4 pk;
            #pragma unroll
            for (int r = 0; r < 4; ++r) pk[r] = f2bf(fmaxf(c1[ht][r], 0.f));
            *(bf16x4*)&h1buf[c*136 + ht*16 + q*4] = pk;
        }
        f32x4 c2[4];
        #pragma unroll
        for (int jt = 0; jt < 4; ++jt) {
            float bi = b2c[jt];
            c2[jt] = (f32x4){bi, bi, bi, bi};
        }
        #pragma unroll
        for (int ks = 0; ks < 4; ++ks) {
            bf16x8 a2 = *(const bf16x8*)&h1buf[c*136 + ks*32 + q*8];
            #pragma unroll
            for (int jt = 0; jt < 4; ++jt)
                c2[jt] = __builtin_amdgcn_mfma_f32_16x16x32_bf16(a2, b2r[jt*4 + ks], c2[jt], 0, 0, 0);
        }
        float part[4];
        #pragma unroll
        for (int r = 0; r < 4; ++r) part[r] = 0.f;
        #pragma unroll
        for (int jt = 0; jt < 4; ++jt)
            #pragma unroll
            for (int r = 0; r < 4; ++r)
                part[r] = fmaf(fmaxf(c2[jt][r], 0.f), w3c[jt], part[r]);
        #pragma unroll
        for (int off = 1; off < 16; off <<= 1)
            #pragma unroll
            for (int r = 0; r < 4; ++r)
                part[r] += __shfl_xor(part[r], off, 16);
        if (c == 0) {
            #pragma unroll
            for (int r = 0; r < 4; ++r) {
                int s_loc = st*16 + q*4 + r;
                float mech = part[r] + bm3v;
                float xv = data[(gs0 + s_loc)*16 + v];   // f32 exact fallback
                out[256 + (gs0 + s_loc)*16 + v] = (hp != 0.f) ? mech : xv;
            }
        }
    }
}

// ---------------------------------------------------------------- launch
extern "C" void kernel_launch(void* const* d_in, const int* in_sizes, int n_in,
                              void* d_out, int out_size, void* d_ws, size_t ws_size,
                              hipStream_t stream)
{
    const float* data = (const float*)d_in[0];
    const float* Ws1  = (const float*)d_in[1];
    const float* bs1  = (const float*)d_in[2];
    const float* Ws2  = (const float*)d_in[3];
    const float* bs2  = (const float*)d_in[4];
    const float* Ws3  = (const float*)d_in[5];
    const float* bs3  = (const float*)d_in[6];
    const float* Wm1  = (const float*)d_in[7];
    const float* bm1  = (const float*)d_in[8];
    const float* Wm2  = (const float*)d_in[9];
    const float* bm2  = (const float*)d_in[10];
    const float* Wm3  = (const float*)d_in[11];
    const float* bm3  = (const float*)d_in[12];
    const float* Wt1  = (const float*)d_in[13];
    const float* bt1  = (const float*)d_in[14];
    const float* Wt2  = (const float*)d_in[15];
    const float* bt2  = (const float*)d_in[16];
    float* out = (float*)d_out;
    (void)d_ws; (void)ws_size; (void)in_sizes; (void)n_in; (void)out_size;

    hipLaunchKernelGGL(k_fused, dim3(248), dim3(512), 0, stream,
                       data, Ws1, bs1, Ws2, bs2, Ws3, bs3,
                       Wm1, bm1, Wm2, bm2, Wm3, bm3,
                       Wt1, bt1, Wt2, bt2, out);
}

// Round 10
// 116.719 us; speedup vs baseline: 1.3604x; 1.1634x over previous
//
#include <hip/hip_runtime.h>
#include <hip/hip_bf16.h>

// CausalGraphDiscovery on MI355X. f32 buffers holding bf16-rounded values.
// Round 16: EXACT r5 restoration (best proven: 115.5us, VGPR 88, no spill)
// + zero-register L2 warm touches for Ws1/Ws2/Ws3.
//   r9 post-mortem: r8's spill signature (VGPR 128, WRITE 12MB) persisted
//   WITHOUT the register prefetch -> cause was the merged 2-pair block's
//   deep pipeline hitting the 128-VGPR cap. Pair-merge DISQUALIFIED (4th
//   failed route: rotation r6, flags r7, reg-residency r8, pair-merge r9).
//   Single addition vs r5: each mech block xor-touches one dword per 64B
//   line of Ws1(8/thread)/Ws2(4)/Ws3(4) at t=0 -- lockstep across blocks
//   (TCC merge), ~1.5MB working set resident in 4MB/XCD L2, consumed
//   4-10us later by S5/S7/S9 at L2-hit latency instead of poison-dirty
//   HBM latency. No register residency -> no spill risk. Discard via xor
//   + never-true guarded store to d_ws (r0-proven DCE defeat).
//
// Grid: 368 blocks x 512 threads.
//   bid   0..127: mech block (v = bid>>3, chunk = bid&7 -> 1024 samples)
//   bid 128..367: pair MLP block p = bid-128 (exact r5 code)
//   bid 0 additionally writes adj + scores diagonal.
//
// d_out (f32): [0,256) adj | [256,131328) predictions | [131328,131584) scores
// d_ws: only [0] as DCE-defeat dummy target.

typedef __attribute__((ext_vector_type(8))) short bf16x8;
typedef __attribute__((ext_vector_type(4))) short bf16x4;
typedef __attribute__((ext_vector_type(4))) float f32x4;

#define DEV __device__ __forceinline__
DEV short f2bf(float f){ __hip_bfloat16 h = __float2bfloat16(f); short s; __builtin_memcpy(&s,&h,2); return s; }

// ---- LDS union ----
// avT stride 532: multiple of 4 (16B float4 rows); 532 % 32 == 20 -> cov
// reads ~2-way conflicts (free). avT reused as red2[] K-split scratch.
struct GraphSm {
    float avT[16 * 532];   // av transposed: avT[v][s]; later red2 scratch
    float part[512];       // cov partials
    float corr[256];
    float h1[256];
    float h2[128];         // per-var partials, later layer-2 output
    float adj[256];
};                          // 39680 B
struct MechSm {
    short W2T[64 * 136];    // Wm2^T bf16, padded row 136       17408 B
    short H1[8][16 * 136];  // per-wave h1 staging              34816 B
    float W1[16 * 128];     // layer-1 weights, mask+self folded 8192 B
    float B1[128];
    float B2[64];
    float W3[64];
};                          // 61440 B
struct PairSm {
    float w0[32], w1[32], bb[32], w2[32];
    float red[512];
    float b2s;
};
union SmU { GraphSm g; MechSm m; PairSm p; };

__global__ void __launch_bounds__(512, 2) k_fused(
    const float* __restrict__ data,
    const float* __restrict__ Ws1, const float* __restrict__ bs1,
    const float* __restrict__ Ws2, const float* __restrict__ bs2,
    const float* __restrict__ Ws3, const float* __restrict__ bs3,
    const float* __restrict__ Wm1, const float* __restrict__ bm1,
    const float* __restrict__ Wm2, const float* __restrict__ bm2,
    const float* __restrict__ Wm3, const float* __restrict__ bm3,
    const float* __restrict__ Wt1, const float* __restrict__ bt1,
    const float* __restrict__ Wt2, const float* __restrict__ bt2,
    float* __restrict__ wsf, float* __restrict__ out)
{
    __shared__ __align__(16) SmU sm;
    int tid = threadIdx.x, bid = blockIdx.x;

    if (bid >= 128) {
        // ========= pair MLP block (p = bid-128) — EXACT r5 code =========
        int p = bid - 128;
        int i = p / 15, jr = p % 15;
        int j = jr + (jr >= i ? 1 : 0);
        if (tid < 32) {
            sm.p.w0[tid] = Wt1[p*64 + tid];
            sm.p.w1[tid] = Wt1[p*64 + 32 + tid];
            sm.p.bb[tid] = bt1[p*32 + tid];
            sm.p.w2[tid] = Wt2[p*32 + tid];
        }
        if (tid == 0) sm.p.b2s = bt2[p];
        __syncthreads();
        float b2sv = sm.p.b2s;
        float acc = 0.f;
        float nxa = data[tid*16 + i];      // 1-ahead prefetch pipeline
        float nxb = data[tid*16 + j];
        for (int it = 0; it < 16; ++it) {
            float xa = nxa, xb = nxb;
            if (it < 15) {
                int sn = (it+1)*512 + tid;
                nxa = data[sn*16 + i];
                nxb = data[sn*16 + j];
            }
            float za = 0.f, zb = 0.f;      // 2-way ILP split of serial chain
            #pragma unroll
            for (int h = 0; h < 32; h += 2) {
                float t1 = fmaf(xa, sm.p.w0[h],   fmaf(xb, sm.p.w1[h],   sm.p.bb[h]));
                za = fmaf(fmaxf(t1, 0.f), sm.p.w2[h],   za);
                float t2 = fmaf(xa, sm.p.w0[h+1], fmaf(xb, sm.p.w1[h+1], sm.p.bb[h+1]));
                zb = fmaf(fmaxf(t2, 0.f), sm.p.w2[h+1], zb);
            }
            float z = b2sv + za + zb;
            acc += __builtin_amdgcn_rcpf(1.f + __expf(-z));
        }
        sm.p.red[tid] = acc;
        __syncthreads();
        for (int off = 256; off > 0; off >>= 1) {
            if (tid < off) sm.p.red[tid] += sm.p.red[tid + off];
            __syncthreads();
        }
        if (tid == 0) out[256 + 131072 + i*16 + j] = sm.p.red[0] * (1.f/8192.f);
        return;
    }

    // ==================== mech block (v, chunk) — r5 path ===============
    int v = bid >> 3, chunk = bid & 7;
    int gs0 = chunk * 1024;                // 1024 samples per block

    // ---- t=0 prefetch: phase-B weights + graph biases (no dependencies) --
    float pf_wm1[4];
    #pragma unroll
    for (int r = 0; r < 4; ++r) {
        int e = tid + 512*r;               // e < 2048
        int k = e >> 7, h = e & 127;
        pf_wm1[r] = 0.f;
        if (k != v) {
            int p = k - (k > v ? 1 : 0);
            pf_wm1[r] = Wm1[v*1920 + p*128 + h];
        }
    }
    float4 pf_wm2[4];
    {
        const float* wp = Wm2 + v*8192 + tid*16;
        #pragma unroll
        for (int m4 = 0; m4 < 4; ++m4) pf_wm2[m4] = *(const float4*)&wp[m4*4];
    }
    float b1r  = bm1[v*128 + (tid & 127)];
    float b2r_ = bm2[v*64  + (tid & 63)];
    float w3r  = Wm3[v*64  + (tid & 63)];
    float bm3v = bm3[v];
    float bs1r = bs1[tid & 255];
    float bs2r = bs2[tid & 127];
    float bs3r = bs3[tid & 255];

    // ---- L2 warm: xor-touch one dword per 64B line of Ws1/Ws2/Ws3 -------
    //   Lockstep addresses across all mech blocks (TCC merge+broadcast).
    //   Consumed 4-10us later by S5/S7/S9 at L2-hit latency. No register
    //   residency (xor chain), no spill risk. DCE-defeat store is
    //   dynamically never taken (r0-proven pattern).
    unsigned xr = 0;
    {
        const unsigned* u1 = (const unsigned*)Ws1;
        const unsigned* u2 = (const unsigned*)Ws2;
        const unsigned* u3 = (const unsigned*)Ws3;
        #pragma unroll
        for (int k = 0; k < 8; ++k) xr ^= u1[(tid + 512*k) * 16];   // 256 KB
        #pragma unroll
        for (int k = 0; k < 4; ++k) xr ^= u2[(tid + 512*k) * 16];   // 128 KB
        #pragma unroll
        for (int k = 0; k < 4; ++k) xr ^= u3[(tid + 512*k) * 16];   // 128 KB
    }
    if (xr == 0x9E3779B9u) wsf[0] = 0.f;   // defeat DCE; never taken

    // ---------- phase A: redundant graph chain (all f32) -----------------
    {   // S1: av[v][s] = mean over 16 batches; coalesced float4 loads
        int vb = (tid & 3) * 4, sg = tid >> 2;     // sg in 0..127
        for (int k = 0; k < 4; ++k) {
            int s = sg + k*128;
            float ax=0.f, ay=0.f, az=0.f, aw=0.f;
            #pragma unroll
            for (int b = 0; b < 16; ++b) {
                float4 d4 = *(const float4*)&data[b*8192 + s*16 + vb];
                ax += d4.x; ay += d4.y; az += d4.z; aw += d4.w;
            }
            sm.g.avT[(vb+0)*532 + s] = ax * 0.0625f;
            sm.g.avT[(vb+1)*532 + s] = ay * 0.0625f;
            sm.g.avT[(vb+2)*532 + s] = az * 0.0625f;
            sm.g.avT[(vb+3)*532 + s] = aw * 0.0625f;
        }
    }
    __syncthreads();
    // S2: per-variable partial sums over SEQ -> h2[128] (scratch)
    if (tid < 128) {
        int vv = tid >> 3, sgm = tid & 7;
        const float* rp = &sm.g.avT[vv*532 + sgm*64];
        float a0=0.f, a1=0.f, a2=0.f, a3=0.f;
        for (int s = 0; s < 64; s += 4) {
            float4 fa = *(const float4*)&rp[s];
            a0 += fa.x; a1 += fa.y; a2 += fa.z; a3 += fa.w;
        }
        sm.g.h2[tid] = (a0+a1)+(a2+a3);
    }
    __syncthreads();
    // S3: cov partials (s-range split in 2) + per-thread means into regs
    int ci, cj; float mci, mcj;
    {
        int t = tid & 255, hh = tid >> 8;
        ci = t >> 4; cj = t & 15;
        mci = 0.f; mcj = 0.f;
        #pragma unroll
        for (int q = 0; q < 8; ++q) { mci += sm.g.h2[ci*8 + q]; mcj += sm.g.h2[cj*8 + q]; }
        mci *= (1.f/512.f); mcj *= (1.f/512.f);
        const float* pi_ = &sm.g.avT[ci*532 + hh*256];
        const float* pj_ = &sm.g.avT[cj*532 + hh*256];
        float a0=0.f, a1=0.f, a2=0.f, a3=0.f;
        #pragma unroll 8
        for (int s = 0; s < 256; s += 4) {
            float4 fa = *(const float4*)&pi_[s];
            float4 fb = *(const float4*)&pj_[s];
            a0 = fmaf(fa.x, fb.x, a0); a1 = fmaf(fa.y, fb.y, a1);
            a2 = fmaf(fa.z, fb.z, a2); a3 = fmaf(fa.w, fb.w, a3);
        }
        sm.g.part[tid] = (a0+a1)+(a2+a3);
    }
    __syncthreads();
    // S4: corr directly (per-thread redundant diag cov)
    if (tid < 256) {
        float cij = sm.g.part[tid] + sm.g.part[256 + tid] - 512.f*mci*mcj;
        float cii = sm.g.part[ci*17] + sm.g.part[256 + ci*17] - 512.f*mci*mci;
        float cjj = sm.g.part[cj*17] + sm.g.part[256 + cj*17] - 512.f*mcj*mcj;
        float den = sqrtf(fmaxf(cii, 0.f)) * sqrtf(fmaxf(cjj, 0.f));
        sm.g.corr[tid] = (den > 0.f && ci != cj) ? fabsf(cij/den) : 0.f;
    }
    __syncthreads();

    float* red2 = sm.g.avT;     // avT dead after S3: reuse as K-split scratch

    {   // S5 layer1: 256 outs; float4-row loads, 8 K-splits of 32
        int o4 = tid & 63, ks = tid >> 6;
        const float* W1p = Ws1 + ks*32*256 + o4*4;
        const float* cp  = sm.g.corr + ks*32;
        float ax=0.f, ay=0.f, az=0.f, aw=0.f;
        float bx=0.f, by=0.f, bz=0.f, bw=0.f;
        #pragma unroll 8
        for (int i = 0; i < 32; i += 2) {
            float4 w0 = *(const float4*)&W1p[(i  )*256];
            float4 w1 = *(const float4*)&W1p[(i+1)*256];
            float c0 = cp[i], c1 = cp[i+1];
            ax=fmaf(c0,w0.x,ax); ay=fmaf(c0,w0.y,ay); az=fmaf(c0,w0.z,az); aw=fmaf(c0,w0.w,aw);
            bx=fmaf(c1,w1.x,bx); by=fmaf(c1,w1.y,by); bz=fmaf(c1,w1.z,bz); bw=fmaf(c1,w1.w,bw);
        }
        float4 r4; r4.x=ax+bx; r4.y=ay+by; r4.z=az+bz; r4.w=aw+bw;
        *(float4*)&red2[ks*256 + o4*4] = r4;
    }
    __syncthreads();
    // S6: h1 reduce (+prefetched bs1)
    if (tid < 256) {
        float s = bs1r;
        #pragma unroll
        for (int k2 = 0; k2 < 8; ++k2) s += red2[k2*256 + tid];
        sm.g.h1[tid] = fmaxf(s, 0.f);
    }
    __syncthreads();
    {   // S7 layer2: 128 outs; 16 K-splits of 16 -> 16 loads/thread, 1 group
        int o4 = tid & 31, ks = tid >> 5;
        const float* W2p = Ws2 + ks*16*128 + o4*4;
        const float* cp  = sm.g.h1 + ks*16;
        float ax=0.f, ay=0.f, az=0.f, aw=0.f;
        float bx=0.f, by=0.f, bz=0.f, bw=0.f;
        #pragma unroll
        for (int i = 0; i < 16; i += 2) {
            float4 w0 = *(const float4*)&W2p[(i  )*128];
            float4 w1 = *(const float4*)&W2p[(i+1)*128];
            float c0 = cp[i], c1 = cp[i+1];
            ax=fmaf(c0,w0.x,ax); ay=fmaf(c0,w0.y,ay); az=fmaf(c0,w0.z,az); aw=fmaf(c0,w0.w,aw);
            bx=fmaf(c1,w1.x,bx); by=fmaf(c1,w1.y,by); bz=fmaf(c1,w1.z,bz); bw=fmaf(c1,w1.w,bw);
        }
        float4 r4; r4.x=ax+bx; r4.y=ay+by; r4.z=az+bz; r4.w=aw+bw;
        *(float4*)&red2[ks*128 + o4*4] = r4;
    }
    __syncthreads();
    // S8: h2 reduce (+prefetched bs2)
    if (tid < 128) {
        float s = bs2r;
        #pragma unroll
        for (int k2 = 0; k2 < 16; ++k2) s += red2[k2*128 + tid];
        sm.g.h2[tid] = fmaxf(s, 0.f);
    }
    __syncthreads();
    {   // S9 layer3: 256 outs; 8 K-splits of 16 -> 16 loads/thread, 1 group
        int o4 = tid & 63, ks = tid >> 6;
        const float* W3p = Ws3 + ks*16*256 + o4*4;
        const float* cp  = sm.g.h2 + ks*16;
        float ax=0.f, ay=0.f, az=0.f, aw=0.f;
        float bx=0.f, by=0.f, bz=0.f, bw=0.f;
        #pragma unroll
        for (int i = 0; i < 16; i += 2) {
            float4 w0 = *(const float4*)&W3p[(i  )*256];
            float4 w1 = *(const float4*)&W3p[(i+1)*256];
            float c0 = cp[i], c1 = cp[i+1];
            ax=fmaf(c0,w0.x,ax); ay=fmaf(c0,w0.y,ay); az=fmaf(c0,w0.z,az); aw=fmaf(c0,w0.w,aw);
            bx=fmaf(c1,w1.x,bx); by=fmaf(c1,w1.y,by); bz=fmaf(c1,w1.z,bz); bw=fmaf(c1,w1.w,bw);
        }
        float4 r4; r4.x=ax+bx; r4.y=ay+by; r4.z=az+bz; r4.w=aw+bw;
        *(float4*)&red2[ks*256 + o4*4] = r4;
    }
    __syncthreads();
    // S10: adj (+prefetched bs3)
    if (tid < 256) {
        float z = bs3r;
        #pragma unroll
        for (int k2 = 0; k2 < 8; ++k2) z += red2[k2*256 + tid];
        float a = 1.f / (1.f + expf(-z));          // precise: feeds 0.5 threshold
        int r = tid >> 4, cc = tid & 15;
        float adjv = (r < cc) ? a : 0.f;           // triu(adj,1)
        sm.g.adj[tid] = adjv;
        if (bid == 0) out[tid] = adjv;             // one block owns adj write
    }
    if (bid == 0 && tid >= 256 && tid < 272)
        out[256 + 131072 + (tid-256)*17] = 0.f;    // scores diagonal
    __syncthreads();

    // S11: phase-B LDS staging purely from prefetched registers + adj reads.
    #pragma unroll
    for (int r = 0; r < 4; ++r) {
        int e = tid + 512*r;
        int k = e >> 7;
        float val = 0.f;
        if (k != v && sm.g.adj[k*16 + v] > 0.5f) val = pf_wm1[r];
        sm.m.W1[e] = val;
    }
    float hp = 0.f;
    #pragma unroll
    for (int k = 0; k < 16; ++k)
        if (k != v && sm.g.adj[k*16 + v] > 0.5f) hp = 1.f;
    #pragma unroll
    for (int m4 = 0; m4 < 4; ++m4) {
        float4 w4 = pf_wm2[m4];
        int e0 = tid*16 + m4*4;
        int h = e0 >> 6;
        int jj0 = e0 & 63;
        sm.m.W2T[(jj0+0)*136 + h] = f2bf(w4.x);
        sm.m.W2T[(jj0+1)*136 + h] = f2bf(w4.y);
        sm.m.W2T[(jj0+2)*136 + h] = f2bf(w4.z);
        sm.m.W2T[(jj0+3)*136 + h] = f2bf(w4.w);
    }
    if (tid < 128) sm.m.B1[tid] = b1r;
    else if (tid < 192) sm.m.B2[tid - 128] = b2r_;
    else if (tid < 256) sm.m.W3[tid - 192] = w3r;
    __syncthreads();

    // ---------- phase B: bf16-MFMA mech MLP (1024 samples) ---------------
    int lane = tid & 63, wid = tid >> 6;           // wid 0..7
    int c = lane & 15, q = lane >> 4;

    bf16x8 a1f[8];
    #pragma unroll
    for (int ht = 0; ht < 8; ++ht) {
        #pragma unroll
        for (int jj = 0; jj < 8; ++jj) {
            int k = q*8 + jj;
            float w = (k < 16) ? sm.m.W1[k*128 + ht*16 + c] : 0.f;
            a1f[ht][jj] = f2bf(w);
        }
    }
    bf16x8 b2r[16];
    #pragma unroll
    for (int jt = 0; jt < 4; ++jt)
        #pragma unroll
        for (int ks = 0; ks < 4; ++ks)
            b2r[jt*4 + ks] = *(const bf16x8*)&sm.m.W2T[(jt*16 + c)*136 + ks*32 + q*8];
    float w3c[4], b2c[4];
    #pragma unroll
    for (int jt = 0; jt < 4; ++jt) { w3c[jt] = sm.m.W3[jt*16 + c]; b2c[jt] = sm.m.B2[jt*16 + c]; }

    short* h1buf = sm.m.H1[wid];
    bool act = (q < 2);

    // 1-ahead software pipeline on the X-tile loads
    float4 u0c, u1c;
    {
        int st0 = wid*8;
        if (act) {
            const float* xp = &data[(gs0 + st0*16 + c)*16 + q*8];
            u0c = *(const float4*)xp;
            u1c = *(const float4*)(xp + 4);
        }
    }

    for (int stl = 0; stl < 8; ++stl) {
        int st = wid*8 + stl;                       // 0..63 (1024 samples)
        float4 u0 = u0c, u1 = u1c;
        if (stl < 7 && act) {                       // prefetch next pass
            const float* xp = &data[(gs0 + (st+1)*16 + c)*16 + q*8];
            u0c = *(const float4*)xp;
            u1c = *(const float4*)(xp + 4);
        }
        bf16x8 xb;
        #pragma unroll
        for (int i2 = 0; i2 < 8; ++i2) xb[i2] = 0;
        if (act) {
            xb[0] = f2bf(u0.x); xb[1] = f2bf(u0.y);
            xb[2] = f2bf(u0.z); xb[3] = f2bf(u0.w);
            xb[4] = f2bf(u1.x); xb[5] = f2bf(u1.y);
            xb[6] = f2bf(u1.z); xb[7] = f2bf(u1.w);
        }
        f32x4 c1[8];
        #pragma unroll
        for (int ht = 0; ht < 8; ++ht) c1[ht] = *(const f32x4*)&sm.m.B1[ht*16 + q*4];
        #pragma unroll
        for (int ht = 0; ht < 8; ++ht)
            c1[ht] = __builtin_amdgcn_mfma_f32_16x16x32_bf16(a1f[ht], xb, c1[ht], 0, 0, 0);
        #pragma unroll
        for (int ht = 0; ht < 8; ++ht) {
            bf16x4 pk;
            #pragma unroll
            for (int r = 0; r < 4; ++r) pk[r] = f2bf(fmaxf(c1[ht][r], 0.f));
            *(bf16x4*)&h1buf[c*136 + ht*16 + q*4] = pk;
        }
        f32x4 c2[4];
        #pragma unroll
        for (int jt = 0; jt < 4; ++jt) {
            float bi = b2c[jt];
            c2[jt] = (f32x4){bi, bi, bi, bi};
        }
        #pragma unroll
        for (int ks = 0; ks < 4; ++ks) {
            bf16x8 a2 = *(const bf16x8*)&h1buf[c*136 + ks*32 + q*8];
            #pragma unroll
            for (int jt = 0; jt < 4; ++jt)
                c2[jt] = __builtin_amdgcn_mfma_f32_16x16x32_bf16(a2, b2r[jt*4 + ks], c2[jt], 0, 0, 0);
        }
        float part[4];
        #pragma unroll
        for (int r = 0; r < 4; ++r) part[r] = 0.f;
        #pragma unroll
        for (int jt = 0; jt < 4; ++jt)
            #pragma unroll
            for (int r = 0; r < 4; ++r)
                part[r] = fmaf(fmaxf(c2[jt][r], 0.f), w3c[jt], part[r]);
        #pragma unroll
        for (int off = 1; off < 16; off <<= 1)
            #pragma unroll
            for (int r = 0; r < 4; ++r)
                part[r] += __shfl_xor(part[r], off, 16);
        if (c == 0) {
            #pragma unroll
            for (int r = 0; r < 4; ++r) {
                int s_loc = st*16 + q*4 + r;
                float mech = part[r] + bm3v;
                float xv = data[(gs0 + s_loc)*16 + v];   // f32 exact fallback
                out[256 + (gs0 + s_loc)*16 + v] = (hp != 0.f) ? mech : xv;
            }
        }
    }
}

// ---------------------------------------------------------------- launch
extern "C" void kernel_launch(void* const* d_in, const int* in_sizes, int n_in,
                              void* d_out, int out_size, void* d_ws, size_t ws_size,
                              hipStream_t stream)
{
    const float* data = (const float*)d_in[0];
    const float* Ws1  = (const float*)d_in[1];
    const float* bs1  = (const float*)d_in[2];
    const float* Ws2  = (const float*)d_in[3];
    const float* bs2  = (const float*)d_in[4];
    const float* Ws3  = (const float*)d_in[5];
    const float* bs3  = (const float*)d_in[6];
    const float* Wm1  = (const float*)d_in[7];
    const float* bm1  = (const float*)d_in[8];
    const float* Wm2  = (const float*)d_in[9];
    const float* bm2  = (const float*)d_in[10];
    const float* Wm3  = (const float*)d_in[11];
    const float* bm3  = (const float*)d_in[12];
    const float* Wt1  = (const float*)d_in[13];
    const float* bt1  = (const float*)d_in[14];
    const float* Wt2  = (const float*)d_in[15];
    const float* bt2  = (const float*)d_in[16];
    float* wsf = (float*)d_ws;
    float* out = (float*)d_out;
    (void)ws_size; (void)in_sizes; (void)n_in; (void)out_size;

    hipLaunchKernelGGL(k_fused, dim3(368), dim3(512), 0, stream,
                       data, Ws1, bs1, Ws2, bs2, Ws3, bs3,
                       Wm1, bm1, Wm2, bm2, Wm3, bm3,
                       Wt1, bt1, Wt2, bt2, wsf, out);
}